// Round 25
// baseline (555.333 us; speedup 1.0000x reference)
//
#include <hip/hip_runtime.h>
#include <cstdint>
#include <cstddef>

#define DEV __device__ __forceinline__

typedef __bf16 bf16;
typedef __bf16 bf16x8 __attribute__((ext_vector_type(8)));
typedef __bf16 bf16x4v __attribute__((ext_vector_type(4)));
typedef float  f32x4  __attribute__((ext_vector_type(4)));
typedef float  f32x16 __attribute__((ext_vector_type(16)));
typedef unsigned int uint4v __attribute__((ext_vector_type(4)));

static constexpr int D_   = 1024;
static constexpr int FFN_ = 4096;
static constexpr int NH_  = 16;
static constexpr int HD_  = 64;
static constexpr int SEQ_ = 1024;
static constexpr int T_   = 4 * SEQ_;   // 4096 tokens
static constexpr float L2E_ = 1.4426950408889634f;

// tanh-form GELU via exp2+rcp (~6 VALU ops vs ~22 for erff; |err|<=1e-3, subdominant to bf16 hh cast)
DEV float gelu_f(float x) {
  float g2 = x * fmaf(-0.102944f, x * x, -2.302212f);   // -log2e*1.5957691*(x+0.044715x^3)/x
  return x * __builtin_amdgcn_rcpf(1.f + exp2f(g2));
}

DEV unsigned pk2h(float a, float b) {
  unsigned ua = __builtin_bit_cast(unsigned short, (bf16)a);
  unsigned ub = __builtin_bit_cast(unsigned short, (bf16)b);
  return ua | (ub << 16);
}
DEV unsigned pk2l(float a, float b) {
  bf16 ha = (bf16)a, hb = (bf16)b;
  unsigned ua = __builtin_bit_cast(unsigned short, (bf16)(a - (float)ha));
  unsigned ub = __builtin_bit_cast(unsigned short, (bf16)(b - (float)hb));
  return ua | (ub << 16);
}
DEV bf16x8 mk8(unsigned w0, unsigned w1, unsigned w2, unsigned w3) {
  uint4v v = {w0, w1, w2, w3};
  return __builtin_bit_cast(bf16x8, v);
}

// ============================ conversions ============================
// Attention path: hidden(4M) | qw(1M) | kw(1M) | vw(1M) | ow(1M) elems, each row [1024] fp32
// -> contiguous bf16 [8192 rows][2048] hi|lo split at single dst base.
__global__ __launch_bounds__(256) void k_cvt_split_all(
    const float* __restrict__ h, const float* __restrict__ qw, const float* __restrict__ kw,
    const float* __restrict__ vw, const float* __restrict__ ow, bf16* __restrict__ out)
{
  int i = (blockIdx.x * 256 + threadIdx.x) * 4;
  if (i >= (8 << 20)) return;
  int seg = i >> 20;
  const float* src; int si;
  if (seg < 4)       { src = h;  si = i; }
  else if (seg == 4) { src = qw; si = i - (4 << 20); }
  else if (seg == 5) { src = kw; si = i - (5 << 20); }
  else if (seg == 6) { src = vw; si = i - (6 << 20); }
  else               { src = ow; si = i - (7 << 20); }
  float4 v = *(const float4*)(src + si);
  int r = i >> 10, c = i & 1023;
  bf16* base = out + (size_t)r * 2048 + c;
  float xs[4] = {v.x, v.y, v.z, v.w};
  #pragma unroll
  for (int j = 0; j < 4; ++j) {
    float x = xs[j];
    bf16 hi = (bf16)x;
    bf16 lo = (bf16)(x - (float)hi);
    base[j]        = hi;
    base[1024 + j] = lo;
  }
}

// ============================ GEMM (C = A @ B^T), TMxTN tile, BK=32 ============================
// SPLIT: A,B are [rows][2048] hi|lo; virtual K=3072: kt 0..31:(Ah,Bh) 32..63:(Al,Bh) 64..95:(Ah,Bl)
// FUSED (FF1/FF2): bx<SBX = shared branch; bx>=SBX = expert branch (weight e+1, row offset 4096).
// OPROJ/FF2 split-K x2: chunk z handles kt [z*nk,(z+1)*nk); disjoint partials, no atomics.
// FF2 XCD swizzle: 1D 1088 blocks, work=(gid&7)*136+(gid>>3), by-fastest -> same-XCD share A tiles.
// NEWSYNC (all GEMMs): counted-vmcnt 2-barrier sync — issue stage early, wait only the PREVIOUS
// iter's 4 loads (vmcnt(4)), raw s_barrier before reads (RAW) and after MFMA (WAR). R22 best config
// (522.0us): LDSSWZ removed (R23: conflicts 8.9M->0 but timing flat -> LDS reads not critical path);
// depth-2 ring removed (R24: neutral). 2-barrier 128^2 family is at its structural ceiling (~634 TF
// FF1 vs documented 2-phase ceiling 655-682 TF, m230/m248).
enum { EPI_QKV = 0, EPI_OPROJ, EPI_FF1, EPI_FF2 };

DEV int map_akt(int kt, bool split) { return split ? (kt < 64 ? kt : kt - 64) : kt; }
DEV int map_bkt(int kt, bool split) { return split ? (kt < 32 ? kt : kt - 32) : kt; }

template<int EPI, bool SPLIT, int TM, int TN, bool NEWSYNC>
__global__ __launch_bounds__(256)
void k_gemm(const bf16* __restrict__ A, const bf16* __restrict__ Bw,
            const float* __restrict__ bias, const float* __restrict__ bias2,
            const float* __restrict__ bias3, const float* __restrict__ resid,
            float* __restrict__ outF, bf16* __restrict__ outB,
            bf16* __restrict__ o2, bf16* __restrict__ o3,
            const int* __restrict__ perm, const int* __restrict__ seg,
            int Kphys, int nk, float scale)
{
  constexpr bool FUSED = (EPI == EPI_FF1 || EPI == EPI_FF2);
  constexpr int  NCOL  = (EPI == EPI_FF1) ? 4096 : 1024;   // expert weight rows
  constexpr int  SBX   = 4096 / TM;                        // shared-branch block count
  constexpr int  MF    = (TN == 128) ? (TM / 32) : (TM / 64);
  constexpr int  AISS  = TM / 64;
  constexpr int  BISS  = TN / 64;

  __shared__ __align__(16) bf16 sA[2][TM * 32];
  __shared__ __align__(16) bf16 sB[2][TN * 32];

  const int tid  = threadIdx.x;
  const int lane = tid & 63;
  const int w    = tid >> 6;
  const int lr   = lane & 15, kg = lane >> 4;
  const int wmBase = (TN == 128) ? (w >> 1) * (TM / 2) : w * (TM / 4);
  const int wnBase = (TN == 128) ? (w & 1) * 64 : 0;

  int bx, by, kz = 0;
  if constexpr (EPI == EPI_FF2) {
    int wk = (blockIdx.x & 7) * 136 + (blockIdx.x >> 3);
    kz = wk / 544; int r2 = wk % 544;
    bx = r2 >> 3; by = r2 & 7;                             // by-fastest: share A tiles
  } else {
    bx = blockIdx.x; by = blockIdx.y; kz = blockIdx.z;
  }
  const int ktBase = (EPI == EPI_OPROJ || EPI == EPI_FF2) ? kz * nk : 0;

  const bool expertBlk = FUSED && (bx >= SBX);
  int e = 0;
  if (FUSED && expertBlk) { int r0 = (bx - SBX) * TM; while (e < 3 && r0 >= seg[e + 1]) e++; }
  const bf16* Bp = Bw + (expertBlk ? (size_t)(e + 1) * NCOL * Kphys : 0);

  const bf16* aSrc[AISS]; const bf16* bSrc[BISS];
  #pragma unroll
  for (int i = 0; i < AISS; ++i) {
    int c = tid + i * 256;
    int koff = (c & 3) * 8;
    if (EPI == EPI_FF1 && expertBlk) {
      int pr = perm[(bx - SBX) * TM + (c >> 2)];
      aSrc[i] = A + (size_t)(pr < 0 ? 0 : pr) * Kphys + koff;
    } else {
      aSrc[i] = A + (size_t)(bx * TM + (c >> 2)) * Kphys + koff;
    }
  }
  #pragma unroll
  for (int i = 0; i < BISS; ++i) {
    int c = tid + i * 256;
    int koff = (c & 3) * 8;
    bSrc[i] = Bp + (size_t)(by * TN + (c >> 2)) * Kphys + koff;
  }

  f32x4 acc[MF][4] = {};

  {
    int ak0 = map_akt(ktBase, SPLIT), bk0 = map_bkt(ktBase, SPLIT);
    #pragma unroll
    for (int i = 0; i < AISS; ++i)
      __builtin_amdgcn_global_load_lds((const void*)(aSrc[i] + (size_t)ak0 * 32),
                                       (void*)((char*)sA[0] + (tid + i * 256) * 16), 16, 0, 0);
    #pragma unroll
    for (int i = 0; i < BISS; ++i)
      __builtin_amdgcn_global_load_lds((const void*)(bSrc[i] + (size_t)bk0 * 32),
                                       (void*)((char*)sB[0] + (tid + i * 256) * 16), 16, 0, 0);
  }
  __syncthreads();

  for (int kt = 0; kt < nk; ++kt) {
    const int cur = kt & 1;
    if (kt + 1 < nk) {
      int ak = map_akt(ktBase + kt + 1, SPLIT), bk = map_bkt(ktBase + kt + 1, SPLIT);
      #pragma unroll
      for (int i = 0; i < AISS; ++i)
        __builtin_amdgcn_global_load_lds((const void*)(aSrc[i] + (size_t)ak * 32),
                                         (void*)((char*)sA[cur ^ 1] + (tid + i * 256) * 16), 16, 0, 0);
      #pragma unroll
      for (int i = 0; i < BISS; ++i)
        __builtin_amdgcn_global_load_lds((const void*)(bSrc[i] + (size_t)bk * 32),
                                         (void*)((char*)sB[cur ^ 1] + (tid + i * 256) * 16), 16, 0, 0);
      if constexpr (NEWSYNC) {
        // wait only the PREVIOUS iter's loads (fill `cur`); this iter's 4 stay in flight
        asm volatile("s_waitcnt vmcnt(4)" ::: "memory");
      }
    } else if constexpr (NEWSYNC) {
      asm volatile("s_waitcnt vmcnt(0)" ::: "memory");
    }
    if constexpr (NEWSYNC) {
      asm volatile("s_barrier" ::: "memory");   // RAW: cur visible to all waves
    }
    bf16x8 af[MF], bfr[4];
    #pragma unroll
    for (int m = 0; m < MF; ++m)
      af[m] = *(const bf16x8*)&sA[cur][(wmBase + m * 16 + lr) * 32 + kg * 8];
    #pragma unroll
    for (int n = 0; n < 4; ++n)
      bfr[n] = *(const bf16x8*)&sB[cur][(wnBase + n * 16 + lr) * 32 + kg * 8];
    #pragma unroll
    for (int m = 0; m < MF; ++m)
      #pragma unroll
      for (int n = 0; n < 4; ++n)
        acc[m][n] = __builtin_amdgcn_mfma_f32_16x16x32_bf16(af[m], bfr[n], acc[m][n], 0, 0, 0);
    if constexpr (NEWSYNC) {
      asm volatile("s_barrier" ::: "memory");   // WAR: all reads of cur done before overwrite
    } else {
      __syncthreads();
    }
  }

  // epilogue: C layout col=lane&15, row=(lane>>4)*4+reg
  #pragma unroll
  for (int m = 0; m < MF; ++m) {
    #pragma unroll
    for (int n = 0; n < 4; ++n) {
      int gc = by * TN + wnBase + n * 16 + lr;
      #pragma unroll
      for (int r = 0; r < 4; ++r) {
        int row = bx * TM + wmBase + m * 16 + kg * 4 + r;
        float v = acc[m][n][r];
        if constexpr (EPI == EPI_QKV) {
          const int which = by >> 3;           // 0=Q 1=K 2=V (block-uniform)
          const int wcol = gc & 1023;
          int bq = row >> 10, li = row & 1023, hh = wcol >> 6, d = wcol & 63;
          if (which == 0) {
            float y = (v + bias[wcol]) * scale;
            bf16* base = outB + ((size_t)(bq * NH_ + hh) * SEQ_ + li) * 128 + d;
            bf16 hi = (bf16)y, lo = (bf16)(y - (float)hi);
            base[0] = hi; base[64] = lo;
          } else if (which == 1) {
            float y = v + bias2[wcol];
            bf16* base = o2 + ((size_t)(bq * NH_ + hh) * SEQ_ + li) * 128 + d;
            bf16 hi = (bf16)y, lo = (bf16)(y - (float)hi);
            base[0] = hi; base[64] = lo;
          } else {
            float y = v + bias3[wcol];
            bf16* base = o3 + ((size_t)(bq * NH_ + hh) * HD_ + d) * 2048 + li;
            bf16 hi = (bf16)y, lo = (bf16)(y - (float)hi);
            base[0] = hi; base[1024] = lo;
          }
        } else if constexpr (EPI == EPI_OPROJ) {
          // fp32 split-K partial (bias+resid added in k_ln1gate)
          outF[((size_t)kz * 4096 + row) * 1024 + gc] = v;
        } else if constexpr (EPI == EPI_FF1) {
          float y = v + (expertBlk ? bias2[e * 4096 + gc] : bias[gc]);
          outB[(size_t)row * 4096 + gc] = (bf16)gelu_f(y);
        } else if constexpr (EPI == EPI_FF2) {
          // bf16 partial per K-chunk; bias added in k_final reduce
          o2[((size_t)kz * 8704 + row) * 1024 + gc] = (bf16)v;
        }
      }
    }
  }
}

// ================= fused flash attention + MoE weight conversion =================
// Block-range dispatch: blocks 0..511 = attention (swapped-QK^T, 32x32 MFMA, as before);
// blocks 512..41471 = MoE weight conversion fc1|efc1|fc2|efc2 -> contiguous bf16 (the old k_cvt4).
// Rationale: attn is MFMA/LDS-bound with HBM mostly idle (K/V/mask L2-resident via XCD swizzle);
// cvt is pure BW (~240MB). Fusing hides cvt's ~40-50us serial time in attn's shadow. Branch is
// block-uniform -> __syncthreads safe. Kernel boundary still orders cvt output before route/FF1.
// Weights dst is DISJOINT from all attn buffers in the new layout (O_W1B region below O_A).
__global__ __launch_bounds__(256)
void k_attn_cvt(const bf16* __restrict__ q2, const bf16* __restrict__ k2,
                const bf16* __restrict__ vT2, const float* __restrict__ mask,
                const float* __restrict__ lhm, bf16* __restrict__ ctx2,
                const float* __restrict__ wa, const float* __restrict__ wb,
                const float* __restrict__ wc, const float* __restrict__ wd,
                bf16* __restrict__ wdst)
{
  __shared__ __align__(16) bf16 sK[2][4096];   // 32 keys x [hi64|lo64] (chunk-swizzled rows)
  __shared__ __align__(16) bf16 sV[2][4096];   // 64 d x [32 hi|32 lo] (chunk-swizzled rows)

  if (blockIdx.x >= 512) {
    // ---- conversion body (old k_cvt4): 40960 blocks x 1024 elems ----
    size_t i = ((size_t)(blockIdx.x - 512) * 256 + threadIdx.x) * 4;
    constexpr size_t M1 = 4ull << 20, M2 = 20ull << 20, M3 = 24ull << 20, M4 = 40ull << 20;
    const float* src; size_t si;
    if (i < M1)      { src = wa; si = i; }
    else if (i < M2) { src = wb; si = i - M1; }
    else if (i < M3) { src = wc; si = i - M2; }
    else if (i < M4) { src = wd; si = i - M3; }
    else return;
    float4 v = *(const float4*)(src + si);
    bf16x4v o;
    o[0] = (bf16)v.x; o[1] = (bf16)v.y; o[2] = (bf16)v.z; o[3] = (bf16)v.w;
    *(bf16x4v*)(wdst + i) = o;
    return;
  }

  // ---- attention body (blocks 0..511), unchanged ----
  // XCD swizzle: same-bh blocks land on one XCD's L2.
  const int blk = (blockIdx.x & 7) * 64 + (blockIdx.x >> 3);
  const int bh = blk >> 3, qb = blk & 7;
  const int tid = threadIdx.x;
  const int w = tid >> 6, lane = tid & 63;
  const int lq = lane & 31, hi = lane >> 5;
  const int b = bh >> 4, h = bh & 15;
  const int q0 = qb * 128 + w * 32;

  // Q fragments (B-operand): lane holds row q0+lq, d-elems (hi*8 + j) of each 16-slice
  const bf16* qp = q2 + ((size_t)bh * SEQ_ + q0 + lq) * 128;
  bf16x8 qh[4], ql[4];
  #pragma unroll
  for (int s = 0; s < 4; ++s) {
    qh[s] = *(const bf16x8*)(qp + s * 16 + hi * 8);
    ql[s] = *(const bf16x8*)(qp + 64 + s * 16 + hi * 8);
  }

  const bf16* kp = k2 + (size_t)bh * SEQ_ * 128;
  const bf16* vp = vT2 + (size_t)bh * HD_ * 2048;
  const float* mp = mask + ((size_t)b * SEQ_ + q0 + lq) * SEQ_;

  // cooperative stage of one 32-key tile (K 8KB + V 8KB), pre-swizzled source
  auto stage = [&](int buf, int kb) {
    #pragma unroll
    for (int i = 0; i < 2; ++i) {
      int c = i * 256 + w * 64 + lane;
      // K: 256B rows; chunk swizzle c' = c ^ ((c>>4)&7)
      int cs = c ^ ((c >> 4) & 7);
      __builtin_amdgcn_global_load_lds((const void*)(kp + (size_t)kb * 128 + cs * 8),
                                       (void*)&sK[buf][(size_t)(i * 256 + w * 64) * 8], 16, 0, 0);
      // V: 128B rows [d][8 parts]; part swizzle p' = p ^ (d&7)
      int d = c >> 3, p = (c & 7) ^ (d & 7);
      const bf16* vsrc = vp + (size_t)d * 2048 + (p < 4 ? kb + p * 8 : 1024 + kb + (p - 4) * 8);
      __builtin_amdgcn_global_load_lds((const void*)vsrc,
                                       (void*)&sV[buf][(size_t)(i * 256 + w * 64) * 8], 16, 0, 0);
    }
  };

  float m_run = -1e30f, l_run = 0.f;
  f32x16 ot[2] = {};

  // mask prefetch: lane's query row, 16 keys at {8*r4 + 4*hi + 0..3}
  float4 mreg[4];
  #pragma unroll
  for (int r4 = 0; r4 < 4; ++r4)
    mreg[r4] = *(const float4*)(mp + 8 * r4 + 4 * hi);

  stage(0, 0);
  __syncthreads();

  for (int kc = 0; kc < SEQ_ / 32; ++kc) {
    const int kb = kc * 32;
    const int cur = kc & 1;
    if (kc + 1 < SEQ_ / 32) stage(cur ^ 1, kb + 32);

    const char* kbase = (const char*)sK[cur];
    const char* vbase = (const char*)sV[cur];

    // ---- QK^T (S^T): A = K rows, B = Q regs ----
    f32x16 st = {};
    __builtin_amdgcn_s_setprio(1);
    #pragma unroll
    for (int s = 0; s < 4; ++s) {
      int gh = s * 2 + hi, gl = 8 + s * 2 + hi;
      bf16x8 kh = *(const bf16x8*)(kbase + lq * 256 + ((gh ^ (lq & 7)) << 4));
      bf16x8 kl = *(const bf16x8*)(kbase + lq * 256 + ((gl ^ (lq & 7)) << 4));
      st = __builtin_amdgcn_mfma_f32_32x32x16_bf16(kh, qh[s], st, 0, 0, 0);
      st = __builtin_amdgcn_mfma_f32_32x32x16_bf16(kh, ql[s], st, 0, 0, 0);
      st = __builtin_amdgcn_mfma_f32_32x32x16_bf16(kl, qh[s], st, 0, 0, 0);
    }
    __builtin_amdgcn_s_setprio(0);
    // mask: st[reg] has key (reg&3)+8*(reg>>2)+4*hi
    #pragma unroll
    for (int reg = 0; reg < 16; ++reg)
      st[reg] = fmaf(((const float*)&mreg[reg >> 2])[reg & 3], L2E_, st[reg]);
    if (kc + 1 < SEQ_ / 32) {
      #pragma unroll
      for (int r4 = 0; r4 < 4; ++r4)
        mreg[r4] = *(const float4*)(mp + kb + 32 + 8 * r4 + 4 * hi);
    }

    // ---- softmax: per-lane (one query) ----
    float cm = st[0];
    #pragma unroll
    for (int reg = 1; reg < 16; ++reg) cm = fmaxf(cm, st[reg]);
    cm = fmaxf(cm, __shfl_xor(cm, 32, 64));
    float mnew = fmaxf(m_run, cm);
    float alpha = exp2f(m_run - mnew);
    float p[16];
    #pragma unroll
    for (int reg = 0; reg < 16; ++reg) p[reg] = exp2f(st[reg] - mnew);
    float rs = p[0];
    #pragma unroll
    for (int reg = 1; reg < 16; ++reg) rs += p[reg];
    rs += __shfl_xor(rs, 32, 64);
    l_run = l_run * alpha + rs; m_run = mnew;
    #pragma unroll
    for (int i = 0; i < 16; ++i) { ot[0][i] *= alpha; ot[1][i] *= alpha; }

    // ---- P -> bf16 hi/lo packs, redistribute for PV B-operand ----
    unsigned hA0 = pk2h(p[0], p[1]),  hA1 = pk2h(p[2], p[3]);
    unsigned hB0 = pk2h(p[4], p[5]),  hB1 = pk2h(p[6], p[7]);
    unsigned hC0 = pk2h(p[8], p[9]),  hC1 = pk2h(p[10], p[11]);
    unsigned hD0 = pk2h(p[12], p[13]), hD1 = pk2h(p[14], p[15]);
    unsigned lA0 = pk2l(p[0], p[1]),  lA1 = pk2l(p[2], p[3]);
    unsigned lB0 = pk2l(p[4], p[5]),  lB1 = pk2l(p[6], p[7]);
    unsigned lC0 = pk2l(p[8], p[9]),  lC1 = pk2l(p[10], p[11]);
    unsigned lD0 = pk2l(p[12], p[13]), lD1 = pk2l(p[14], p[15]);
    // exchange: hi=0 needs partner A, hi=1 needs partner B (slice0); C/D for slice1
    unsigned x0 = (unsigned)__shfl_xor((int)(hi ? hA0 : hB0), 32, 64);
    unsigned x1 = (unsigned)__shfl_xor((int)(hi ? hA1 : hB1), 32, 64);
    unsigned x2 = (unsigned)__shfl_xor((int)(hi ? hC0 : hD0), 32, 64);
    unsigned x3 = (unsigned)__shfl_xor((int)(hi ? hC1 : hD1), 32, 64);
    unsigned y0 = (unsigned)__shfl_xor((int)(hi ? lA0 : lB0), 32, 64);
    unsigned y1 = (unsigned)__shfl_xor((int)(hi ? lA1 : lB1), 32, 64);
    unsigned y2 = (unsigned)__shfl_xor((int)(hi ? lC0 : lD0), 32, 64);
    unsigned y3 = (unsigned)__shfl_xor((int)(hi ? lC1 : lD1), 32, 64);
    bf16x8 pb0h = hi ? mk8(x0, x1, hB0, hB1) : mk8(hA0, hA1, x0, x1);
    bf16x8 pb1h = hi ? mk8(x2, x3, hD0, hD1) : mk8(hC0, hC1, x2, x3);
    bf16x8 pb0l = hi ? mk8(y0, y1, lB0, lB1) : mk8(lA0, lA1, y0, y1);
    bf16x8 pb1l = hi ? mk8(y2, y3, lD0, lD1) : mk8(lC0, lC1, y2, y3);

    // ---- PV (O^T): A = V^T rows from LDS, B = P packs ----
    __builtin_amdgcn_s_setprio(1);
    #pragma unroll
    for (int ks = 0; ks < 2; ++ks) {
      bf16x8 pbh = ks ? pb1h : pb0h;
      bf16x8 pbl = ks ? pb1l : pb0l;
      #pragma unroll
      for (int t = 0; t < 2; ++t) {
        int row = t * 32 + lq;
        int gh = ks * 2 + hi, gl = 4 + ks * 2 + hi;
        bf16x8 vh = *(const bf16x8*)(vbase + row * 128 + ((gh ^ (row & 7)) << 4));
        bf16x8 vl = *(const bf16x8*)(vbase + row * 128 + ((gl ^ (row & 7)) << 4));
        ot[t] = __builtin_amdgcn_mfma_f32_32x32x16_bf16(vh, pbh, ot[t], 0, 0, 0);
        ot[t] = __builtin_amdgcn_mfma_f32_32x32x16_bf16(vh, pbl, ot[t], 0, 0, 0);
        ot[t] = __builtin_amdgcn_mfma_f32_32x32x16_bf16(vl, pbh, ot[t], 0, 0, 0);
      }
    }
    __builtin_amdgcn_s_setprio(0);

    __syncthreads();   // drains staging (vmcnt) + LDS reads before buffer swap
  }

  // ---- epilogue: O^T col=lane&31=query (in-lane l_run), row=d ----
  const float rln = lhm[h] / l_run;
  bf16* base = ctx2 + ((size_t)b * SEQ_ + q0 + lq) * 2048;
  #pragma unroll
  for (int t = 0; t < 2; ++t)
    #pragma unroll
    for (int reg = 0; reg < 16; ++reg) {
      int d = (reg & 3) + 8 * (reg >> 2) + 4 * hi + 32 * t;
      int col = h * HD_ + d;
      float y = ot[t][reg] * rln;
      bf16 yh = (bf16)y, yl = (bf16)(y - (float)yh);
      base[col] = yh; base[1024 + col] = yl;
    }
}

// ============================ layernorm+gate / route / final ============================
DEV float blockReduceSum(float v, int tid, float* sm)
{
  #pragma unroll
  for (int d = 1; d < 64; d <<= 1) v += __shfl_xor(v, d, 64);
  if ((tid & 63) == 0) sm[tid >> 6] = v;
  __syncthreads();
  float r = sm[0] + sm[1] + sm[2] + sm[3];
  __syncthreads();
  return r;
}

// OPROJ-reduce + LN1 + gate fused: z = hidden + P0 + P1 + ob; h = LN(z); gate from h.
__global__ __launch_bounds__(256)
void k_ln1gate(const float* __restrict__ resid, const float* __restrict__ Pp, const float* __restrict__ ob,
               const float* __restrict__ gam, const float* __restrict__ bet,
               const float* __restrict__ gw, const float* __restrict__ gb, const int* __restrict__ idxes,
               float* __restrict__ h, bf16* __restrict__ hb,
               float* __restrict__ gv, int* __restrict__ gi)
{
  __shared__ float sm[4];
  __shared__ float red[4][4];
  int t = blockIdx.x, tid = threadIdx.x;
  constexpr size_t CH = 4096ull * 1024ull;
  float4 rv = *(const float4*)(resid + (size_t)t * 1024 + tid * 4);
  float4 p0 = *(const float4*)(Pp + (size_t)t * 1024 + tid * 4);
  float4 p1 = *(const float4*)(Pp + CH + (size_t)t * 1024 + tid * 4);
  float4 bo = *(const float4*)(ob + tid * 4);
  float z0 = rv.x + p0.x + p1.x + bo.x;
  float z1 = rv.y + p0.y + p1.y + bo.y;
  float z2 = rv.z + p0.z + p1.z + bo.z;
  float z3 = rv.w + p0.w + p1.w + bo.w;
  float mean = blockReduceSum(z0 + z1 + z2 + z3, tid, sm) * (1.f / 1024.f);
  float d0 = z0 - mean, d1 = z1 - mean, d2 = z2 - mean, d3 = z3 - mean;
  float var = blockReduceSum(d0*d0 + d1*d1 + d2*d2 + d3*d3, tid, sm) * (1.f / 1024.f);
  float inv = rsqrtf(var + 1e-5f);
  float4 g4 = *(const float4*)(gam + tid * 4);
  float4 b4 = *(const float4*)(bet + tid * 4);
  float y0 = d0 * inv * g4.x + b4.x, y1 = d1 * inv * g4.y + b4.y;
  float y2 = d2 * inv * g4.z + b4.z, y3 = d3 * inv * g4.w + b4.w;
  float4 yo; yo.x = y0; yo.y = y1; yo.z = y2; yo.w = y3;
  *(float4*)(h + (size_t)t * 1024 + tid * 4) = yo;
  bf16x4v hv; hv[0] = (bf16)y0; hv[1] = (bf16)y1; hv[2] = (bf16)y2; hv[3] = (bf16)y3;
  *(bf16x4v*)(hb + (size_t)t * 1024 + tid * 4) = hv;

  // ---- gate ----
  int ds = idxes[t >> 10];
  const float* wg = gw + (size_t)ds * 4096;
  float a[4];
  #pragma unroll
  for (int e = 0; e < 4; ++e) {
    float4 wv = *(const float4*)(wg + e * 1024 + tid * 4);
    a[e] = y0 * wv.x + y1 * wv.y + y2 * wv.z + y3 * wv.w;
  }
  int lane = tid & 63, wid = tid >> 6;
  #pragma unroll
  for (int e = 0; e < 4; ++e) {
    float vv = a[e];
    #pragma unroll
    for (int d = 1; d < 64; d <<= 1) vv += __shfl_xor(vv, d, 64);
    if (lane == 0) red[wid][e] = vv;
  }
  __syncthreads();
  if (tid == 0) {
    float lg[4];
    #pragma unroll
    for (int e = 0; e < 4; ++e) lg[e] = red[0][e] + red[1][e] + red[2][e] + red[3][e] + gb[ds * 4 + e];
    int best = 0; float bv = lg[0];
    #pragma unroll
    for (int e = 1; e < 4; ++e) if (lg[e] > bv) { bv = lg[e]; best = e; }
    float se = 0.f;
    #pragma unroll
    for (int e = 0; e < 4; ++e) se += expf(lg[e] - bv);
    gv[t] = 1.f / se;
    gi[t] = best;
  }
}

// Single-block routing: count -> segments -> scatter (+ inverse map token->expert row).
__global__ __launch_bounds__(1024)
void k_route_all(const int* __restrict__ gi, int* __restrict__ meta,
                 int* __restrict__ perm, int* __restrict__ inv)
{
  __shared__ int cnt[4], seg[5], cur[4];
  int tid = threadIdx.x;
  if (tid < 4) { cnt[tid] = 0; cur[tid] = 0; }
  __syncthreads();
  #pragma unroll
  for (int k = 0; k < 4; ++k) atomicAdd(&cnt[gi[tid + k * 1024]], 1);
  #pragma unroll
  for (int k = 0; k < 5; ++k) { int i = tid + k * 1024; if (i < 4608) perm[i] = -1; }
  __syncthreads();
  if (tid == 0) {
    int s = 0;
    #pragma unroll
    for (int e = 0; e < 4; ++e) { seg[e] = s; s += (cnt[e] + 127) & ~127; }
    seg[4] = s;
    #pragma unroll
    for (int e = 0; e < 5; ++e) meta[8 + e] = seg[e];
  }
  __syncthreads();
  #pragma unroll
  for (int k = 0; k < 4; ++k) {
    int t = tid + k * 1024;
    int e = gi[t];
    int p = atomicAdd(&cur[e], 1);
    int rowp = seg[e] + p;
    perm[rowp] = t;
    inv[t] = rowp;
  }
}

// Final: reduce 2 split-K partials x (shared row + expert row) + fc2b, then LN2 * gate.
__global__ __launch_bounds__(256)
void k_final(const float* __restrict__ h, const bf16* __restrict__ P,
             const float* __restrict__ b2, const float* __restrict__ gam,
             const float* __restrict__ bet, const float* __restrict__ gv,
             const int* __restrict__ inv, float* __restrict__ out)
{
  __shared__ float sm[4];
  int t = blockIdx.x, tid = threadIdx.x;
  constexpr size_t CH = 8704ull * 1024ull;
  int er = 4096 + inv[t];
  bf16x4v q0 = *(const bf16x4v*)(P + (size_t)t * 1024 + tid * 4);
  bf16x4v q1 = *(const bf16x4v*)(P + CH + (size_t)t * 1024 + tid * 4);
  bf16x4v q2 = *(const bf16x4v*)(P + (size_t)er * 1024 + tid * 4);
  bf16x4v q3 = *(const bf16x4v*)(P + CH + (size_t)er * 1024 + tid * 4);
  float4 a = *(const float4*)(h + (size_t)t * 1024 + tid * 4);
  float4 bb = *(const float4*)(b2 + tid * 4);
  float z0 = a.x + (float)q0[0] + (float)q1[0] + (float)q2[0] + (float)q3[0] + bb.x;
  float z1 = a.y + (float)q0[1] + (float)q1[1] + (float)q2[1] + (float)q3[1] + bb.y;
  float z2 = a.z + (float)q0[2] + (float)q1[2] + (float)q2[2] + (float)q3[2] + bb.z;
  float z3 = a.w + (float)q0[3] + (float)q1[3] + (float)q2[3] + (float)q3[3] + bb.w;
  float mean = blockReduceSum(z0 + z1 + z2 + z3, tid, sm) * (1.f / 1024.f);
  float d0 = z0 - mean, d1 = z1 - mean, d2 = z2 - mean, d3 = z3 - mean;
  float var = blockReduceSum(d0*d0 + d1*d1 + d2*d2 + d3*d3, tid, sm) * (1.f / 1024.f);
  float invd = rsqrtf(var + 1e-5f);
  float4 g4 = *(const float4*)(gam + tid * 4);
  float4 b4 = *(const float4*)(bet + tid * 4);
  float gval = gv[t];
  float4 r;
  r.x = gval * (d0 * invd * g4.x + b4.x);
  r.y = gval * (d1 * invd * g4.y + b4.y);
  r.z = gval * (d2 * invd * g4.z + b4.z);
  r.w = gval * (d3 * invd * g4.w + b4.w);
  *(float4*)(out + (size_t)t * 1024 + tid * 4) = r;
}

// ============================ host ============================
extern "C" void kernel_launch(void* const* d_in, const int* in_sizes, int n_in,
                              void* d_out, int out_size, void* d_ws, size_t ws_size,
                              hipStream_t stream)
{
  const float* hidden = (const float*)d_in[0];
  const float* mask   = (const float*)d_in[1];
  const float* lhm    = (const float*)d_in[2];
  const int*   idxes  = (const int*)d_in[3];
  const float* qw = (const float*)d_in[4];
  const float* kw = (const float*)d_in[5];
  const float* vw = (const float*)d_in[6];
  const float* ow = (const float*)d_in[7];
  const float* fc1w  = (const float*)d_in[8];
  const float* fc2w  = (const float*)d_in[9];
  const float* efc1w = (const float*)d_in[10];
  const float* efc2w = (const float*)d_in[11];
  const float* gatew = (const float*)d_in[12];
  const float* qb = (const float*)d_in[13];
  const float* kb = (const float*)d_in[14];
  const float* vb = (const float*)d_in[15];
  const float* ob = (const float*)d_in[16];
  const float* fc1b  = (const float*)d_in[17];
  const float* fc2b  = (const float*)d_in[18];
  const float* efc1b = (const float*)d_in[19];
  const float* gateb = (const float*)d_in[20];
  const float* ln1g = (const float*)d_in[21];
  const float* ln1b = (const float*)d_in[22];
  const float* ln2g = (const float*)d_in[23];
  const float* ln2b = (const float*)d_in[24];
  float* out = (float*)d_out;
  char* ws = (char*)d_ws;

  constexpr size_t MB = 1024ull * 1024ull;
  // persistent
  constexpr size_t O_H    = 0;                     // fp32 h [4096][1024]
  constexpr size_t O_HBF  = O_H + 16 * MB;         // bf16 h
  constexpr size_t O_GV   = O_HBF + 8 * MB;
  constexpr size_t O_GI   = O_GV + 16 * 1024;
  constexpr size_t O_PERM = O_GI + 16 * 1024;      // 4608 ints
  constexpr size_t O_META = O_PERM + 18432;
  constexpr size_t O_INV  = O_META + 256;          // 4096 ints
  constexpr size_t O_U    = (O_INV + 16384 + 255) & ~255ull;
  // MoE weights region (persistent from fused attn+cvt through FF2; DISJOINT from attn overlay)
  constexpr size_t O_W1B  = O_U;                   // [fc1|efc1x4|fc2|efc2x4] contiguous 80 MB bf16
  constexpr size_t O_WE1B = O_W1B + 8 * MB;
  constexpr size_t O_W2B  = O_WE1B + 32 * MB;
  constexpr size_t O_WE2B = O_W2B + 8 * MB;
  // attention-phase overlay at O_A = O_U + 80MB (contiguous split-bf16 block: X2|WQ2 then outputs)
  constexpr size_t O_A    = O_U + 80 * MB;
  constexpr size_t O_X2   = O_A;                   // [4096][2048] bf16
  constexpr size_t O_WQ2  = O_A + 16 * MB;         // [3072][2048]: Q,K,V weights contiguous
  constexpr size_t O_WO2  = O_WQ2 + 12 * MB;       // ow rows inside the contiguous block
  constexpr size_t O_Q2   = O_A + 32 * MB;         // [B*NH*L][128]
  constexpr size_t O_K2   = O_A + 48 * MB;
  constexpr size_t O_VT2  = O_A + 64 * MB;         // [B*NH*HD][2048]
  constexpr size_t O_CTX2 = O_A + 80 * MB;         // [4096][2048]
  constexpr size_t O_HPRE = O_Q2;                  // fp32 2x[4096][1024] OPROJ partials — aliases
                                                   // Q2+K2 (dead after attn; OPROJ reads CTX2/WO2)
  // MoE mid overlay (reuses attn region — X2..CTX2 + HPRE dead after k_ln1gate)
  constexpr size_t O_HHS  = O_A;                   // [4096][4096] bf16 (shared)  — contiguous with
  constexpr size_t O_HHE  = O_A + 32 * MB;         // [4608][4096] bf16 (expert)  — HHS (rows 4096+)
  constexpr size_t O_P    = O_A + 68 * MB;         // 2 x [8704][1024] bf16 split-K partials (34 MB)
  // total footprint: O_A + 102MB = O_U + 182MB — identical to all prior rounds' proven envelope
  (void)ws_size; (void)in_sizes; (void)n_in; (void)out_size;

  dim3 blk(256);
  // ---- phase 1: attention-path conversions (hi|lo split, ONE launch, contiguous dst) ----
  k_cvt_split_all<<<8192, 256, 0, stream>>>(hidden, qw, kw, vw, ow, (bf16*)(ws + O_X2));

  // ---- phase 2: fused QKV projection (N=3072, 768 blocks) ----
  const float qscale = 0.125f * L2E_;   // fold softmax scale and log2e into Q
  k_gemm<EPI_QKV, true, 128, 128, true><<<dim3(32, 24), blk, 0, stream>>>(
      (bf16*)(ws + O_X2), (bf16*)(ws + O_WQ2), qb, kb, vb, nullptr,
      nullptr, (bf16*)(ws + O_Q2), (bf16*)(ws + O_K2), (bf16*)(ws + O_VT2),
      nullptr, nullptr, 2048, 96, qscale);

  // ---- phase 3: FUSED attention (blocks 0..511) + MoE weight conversion (blocks 512..41471) ----
  k_attn_cvt<<<41472, 256, 0, stream>>>((bf16*)(ws + O_Q2), (bf16*)(ws + O_K2), (bf16*)(ws + O_VT2),
                                        mask, lhm, (bf16*)(ws + O_CTX2),
                                        fc1w, efc1w, fc2w, efc2w, (bf16*)(ws + O_W1B));

  // ---- phase 4: output projection (split-K x2, fp32 partials), then fused reduce+LN1+gate ----
  k_gemm<EPI_OPROJ, true, 128, 64, true><<<dim3(32, 16, 2), blk, 0, stream>>>(
      (bf16*)(ws + O_CTX2), (bf16*)(ws + O_WO2), nullptr, nullptr, nullptr, nullptr,
      (float*)(ws + O_HPRE), nullptr, nullptr, nullptr, nullptr, nullptr, 2048, 48, 1.0f);
  k_ln1gate<<<4096, 256, 0, stream>>>(hidden, (float*)(ws + O_HPRE), ob, ln1g, ln1b,
                                      gatew, gateb, idxes,
                                      (float*)(ws + O_H), (bf16*)(ws + O_HBF),
                                      (float*)(ws + O_GV), (int*)(ws + O_GI));

  // ---- phase 5: routing (ONE block; weight conversion already done inside phase 3) ----
  k_route_all<<<1, 1024, 0, stream>>>((int*)(ws + O_GI), (int*)(ws + O_META),
                                      (int*)(ws + O_PERM), (int*)(ws + O_INV));

  // ---- phase 6: fused shared+expert FFN (NEWSYNC counted-vmcnt pipeline) ----
  // FF1: single launch, TM=128, plain 2D grid (68,32)
  k_gemm<EPI_FF1, false, 128, 128, true><<<dim3(68, 32), blk, 0, stream>>>(
      (bf16*)(ws + O_HBF), (bf16*)(ws + O_W1B), fc1b, efc1b, nullptr, nullptr,
      nullptr, (bf16*)(ws + O_HHS), nullptr, nullptr,
      (int*)(ws + O_PERM), (int*)(ws + O_META) + 8, 1024, 32, 1.0f);
  // FF2: split-K x2 into bf16 partials — 1088 blocks, A-grouped per XCD
  k_gemm<EPI_FF2, false, 128, 128, true><<<dim3(1088), blk, 0, stream>>>(
      (bf16*)(ws + O_HHS), (bf16*)(ws + O_W2B), nullptr, nullptr, nullptr, nullptr,
      nullptr, nullptr, (bf16*)(ws + O_P), nullptr,
      nullptr, (int*)(ws + O_META) + 8, 4096, 64, 1.0f);

  // ---- phase 7: final reduce + LN2 * gate_value ----
  k_final<<<4096, 256, 0, stream>>>((float*)(ws + O_H), (bf16*)(ws + O_P), fc2b, ln2g, ln2b,
                                    (float*)(ws + O_GV), (int*)(ws + O_INV), out);
}

// Round 26
// 540.648 us; speedup vs baseline: 1.0272x; 1.0272x over previous
//
#include <hip/hip_runtime.h>
#include <cstdint>
#include <cstddef>

#define DEV __device__ __forceinline__

typedef __bf16 bf16;
typedef __bf16 bf16x8 __attribute__((ext_vector_type(8)));
typedef __bf16 bf16x4v __attribute__((ext_vector_type(4)));
typedef float  f32x4  __attribute__((ext_vector_type(4)));
typedef float  f32x16 __attribute__((ext_vector_type(16)));
typedef unsigned int uint4v __attribute__((ext_vector_type(4)));

static constexpr int D_   = 1024;
static constexpr int FFN_ = 4096;
static constexpr int NH_  = 16;
static constexpr int HD_  = 64;
static constexpr int SEQ_ = 1024;
static constexpr int T_   = 4 * SEQ_;   // 4096 tokens
static constexpr float L2E_ = 1.4426950408889634f;

// tanh-form GELU via exp2+rcp (~6 VALU ops vs ~22 for erff; |err|<=1e-3, subdominant to bf16 hh cast)
DEV float gelu_f(float x) {
  float g2 = x * fmaf(-0.102944f, x * x, -2.302212f);   // -log2e*1.5957691*(x+0.044715x^3)/x
  return x * __builtin_amdgcn_rcpf(1.f + exp2f(g2));
}

DEV unsigned pk2h(float a, float b) {
  unsigned ua = __builtin_bit_cast(unsigned short, (bf16)a);
  unsigned ub = __builtin_bit_cast(unsigned short, (bf16)b);
  return ua | (ub << 16);
}
DEV unsigned pk2l(float a, float b) {
  bf16 ha = (bf16)a, hb = (bf16)b;
  unsigned ua = __builtin_bit_cast(unsigned short, (bf16)(a - (float)ha));
  unsigned ub = __builtin_bit_cast(unsigned short, (bf16)(b - (float)hb));
  return ua | (ub << 16);
}
DEV bf16x8 mk8(unsigned w0, unsigned w1, unsigned w2, unsigned w3) {
  uint4v v = {w0, w1, w2, w3};
  return __builtin_bit_cast(bf16x8, v);
}

// ============================ conversions (merged) ============================
// MoE weights: fc1(4M) | efc1(16M) | fc2(4M) | efc2(16M) elems -> ONE contiguous bf16 dst.
__global__ __launch_bounds__(256) void k_cvt4(const float* __restrict__ a, const float* __restrict__ b,
                                              const float* __restrict__ c, const float* __restrict__ d,
                                              bf16* __restrict__ dst)
{
  size_t i = ((size_t)blockIdx.x * 256 + threadIdx.x) * 4;
  constexpr size_t M1 = 4ull << 20, M2 = 20ull << 20, M3 = 24ull << 20, M4 = 40ull << 20;
  const float* src; size_t si;
  if (i < M1)      { src = a; si = i; }
  else if (i < M2) { src = b; si = i - M1; }
  else if (i < M3) { src = c; si = i - M2; }
  else if (i < M4) { src = d; si = i - M3; }
  else return;
  float4 v = *(const float4*)(src + si);
  bf16x4v o;
  o[0] = (bf16)v.x; o[1] = (bf16)v.y; o[2] = (bf16)v.z; o[3] = (bf16)v.w;
  *(bf16x4v*)(dst + i) = o;
}

// Attention path: hidden(4M) | qw(1M) | kw(1M) | vw(1M) | ow(1M) elems, each row [1024] fp32
// -> contiguous bf16 [8192 rows][2048] hi|lo split at single dst base.
__global__ __launch_bounds__(256) void k_cvt_split_all(
    const float* __restrict__ h, const float* __restrict__ qw, const float* __restrict__ kw,
    const float* __restrict__ vw, const float* __restrict__ ow, bf16* __restrict__ out)
{
  int i = (blockIdx.x * 256 + threadIdx.x) * 4;
  if (i >= (8 << 20)) return;
  int seg = i >> 20;
  const float* src; int si;
  if (seg < 4)       { src = h;  si = i; }
  else if (seg == 4) { src = qw; si = i - (4 << 20); }
  else if (seg == 5) { src = kw; si = i - (5 << 20); }
  else if (seg == 6) { src = vw; si = i - (6 << 20); }
  else               { src = ow; si = i - (7 << 20); }
  float4 v = *(const float4*)(src + si);
  int r = i >> 10, c = i & 1023;
  bf16* base = out + (size_t)r * 2048 + c;
  float xs[4] = {v.x, v.y, v.z, v.w};
  #pragma unroll
  for (int j = 0; j < 4; ++j) {
    float x = xs[j];
    bf16 hi = (bf16)x;
    bf16 lo = (bf16)(x - (float)hi);
    base[j]        = hi;
    base[1024 + j] = lo;
  }
}

// ============================ GEMM (C = A @ B^T), TMxTN tile, BK=32 ============================
// SPLIT: A,B are [rows][2048] hi|lo; virtual K=3072: kt 0..31:(Ah,Bh) 32..63:(Al,Bh) 64..95:(Ah,Bl)
// FUSED (FF1/FF2): bx<SBX = shared branch; bx>=SBX = expert branch (weight e+1, row offset 4096).
// OPROJ/FF2 split-K x2: chunk z handles kt [z*nk,(z+1)*nk); disjoint partials, no atomics.
// FF2 XCD swizzle: 1D 1088 blocks, work=(gid&7)*136+(gid>>3), by-fastest -> same-XCD share A tiles.
// NEWSYNC (all GEMMs): counted-vmcnt 2-barrier sync — issue stage early, wait only the PREVIOUS
// iter's 4 loads (vmcnt(4)), raw s_barrier before reads (RAW) and after MFMA (WAR).
// FINAL configuration (session best, 522.0us R22). Dispositioned levers: HBM traffic (R16/R18:
// FETCH 217->86MB, dur flat), occupancy/tile growth (R11/R14/R16/R19: all cliff), LDS conflicts
// (R23: 8.9M->0, dur flat), depth-2 prefetch (R24: neutral), attn+cvt block fusion (R25: -33us,
// wave-slot contention). GEMMs are at the 2-barrier 128^2 family's structural ceiling.
enum { EPI_QKV = 0, EPI_OPROJ, EPI_FF1, EPI_FF2 };

DEV int map_akt(int kt, bool split) { return split ? (kt < 64 ? kt : kt - 64) : kt; }
DEV int map_bkt(int kt, bool split) { return split ? (kt < 32 ? kt : kt - 32) : kt; }

template<int EPI, bool SPLIT, int TM, int TN, bool NEWSYNC>
__global__ __launch_bounds__(256)
void k_gemm(const bf16* __restrict__ A, const bf16* __restrict__ Bw,
            const float* __restrict__ bias, const float* __restrict__ bias2,
            const float* __restrict__ bias3, const float* __restrict__ resid,
            float* __restrict__ outF, bf16* __restrict__ outB,
            bf16* __restrict__ o2, bf16* __restrict__ o3,
            const int* __restrict__ perm, const int* __restrict__ seg,
            int Kphys, int nk, float scale)
{
  constexpr bool FUSED = (EPI == EPI_FF1 || EPI == EPI_FF2);
  constexpr int  NCOL  = (EPI == EPI_FF1) ? 4096 : 1024;   // expert weight rows
  constexpr int  SBX   = 4096 / TM;                        // shared-branch block count
  constexpr int  MF    = (TN == 128) ? (TM / 32) : (TM / 64);
  constexpr int  AISS  = TM / 64;
  constexpr int  BISS  = TN / 64;

  __shared__ __align__(16) bf16 sA[2][TM * 32];
  __shared__ __align__(16) bf16 sB[2][TN * 32];

  const int tid  = threadIdx.x;
  const int lane = tid & 63;
  const int w    = tid >> 6;
  const int lr   = lane & 15, kg = lane >> 4;
  const int wmBase = (TN == 128) ? (w >> 1) * (TM / 2) : w * (TM / 4);
  const int wnBase = (TN == 128) ? (w & 1) * 64 : 0;

  int bx, by, kz = 0;
  if constexpr (EPI == EPI_FF2) {
    int wk = (blockIdx.x & 7) * 136 + (blockIdx.x >> 3);
    kz = wk / 544; int r2 = wk % 544;
    bx = r2 >> 3; by = r2 & 7;                             // by-fastest: share A tiles
  } else {
    bx = blockIdx.x; by = blockIdx.y; kz = blockIdx.z;
  }
  const int ktBase = (EPI == EPI_OPROJ || EPI == EPI_FF2) ? kz * nk : 0;

  const bool expertBlk = FUSED && (bx >= SBX);
  int e = 0;
  if (FUSED && expertBlk) { int r0 = (bx - SBX) * TM; while (e < 3 && r0 >= seg[e + 1]) e++; }
  const bf16* Bp = Bw + (expertBlk ? (size_t)(e + 1) * NCOL * Kphys : 0);

  const bf16* aSrc[AISS]; const bf16* bSrc[BISS];
  #pragma unroll
  for (int i = 0; i < AISS; ++i) {
    int c = tid + i * 256;
    int koff = (c & 3) * 8;
    if (EPI == EPI_FF1 && expertBlk) {
      int pr = perm[(bx - SBX) * TM + (c >> 2)];
      aSrc[i] = A + (size_t)(pr < 0 ? 0 : pr) * Kphys + koff;
    } else {
      aSrc[i] = A + (size_t)(bx * TM + (c >> 2)) * Kphys + koff;
    }
  }
  #pragma unroll
  for (int i = 0; i < BISS; ++i) {
    int c = tid + i * 256;
    int koff = (c & 3) * 8;
    bSrc[i] = Bp + (size_t)(by * TN + (c >> 2)) * Kphys + koff;
  }

  f32x4 acc[MF][4] = {};

  {
    int ak0 = map_akt(ktBase, SPLIT), bk0 = map_bkt(ktBase, SPLIT);
    #pragma unroll
    for (int i = 0; i < AISS; ++i)
      __builtin_amdgcn_global_load_lds((const void*)(aSrc[i] + (size_t)ak0 * 32),
                                       (void*)((char*)sA[0] + (tid + i * 256) * 16), 16, 0, 0);
    #pragma unroll
    for (int i = 0; i < BISS; ++i)
      __builtin_amdgcn_global_load_lds((const void*)(bSrc[i] + (size_t)bk0 * 32),
                                       (void*)((char*)sB[0] + (tid + i * 256) * 16), 16, 0, 0);
  }
  __syncthreads();

  for (int kt = 0; kt < nk; ++kt) {
    const int cur = kt & 1;
    if (kt + 1 < nk) {
      int ak = map_akt(ktBase + kt + 1, SPLIT), bk = map_bkt(ktBase + kt + 1, SPLIT);
      #pragma unroll
      for (int i = 0; i < AISS; ++i)
        __builtin_amdgcn_global_load_lds((const void*)(aSrc[i] + (size_t)ak * 32),
                                         (void*)((char*)sA[cur ^ 1] + (tid + i * 256) * 16), 16, 0, 0);
      #pragma unroll
      for (int i = 0; i < BISS; ++i)
        __builtin_amdgcn_global_load_lds((const void*)(bSrc[i] + (size_t)bk * 32),
                                         (void*)((char*)sB[cur ^ 1] + (tid + i * 256) * 16), 16, 0, 0);
      if constexpr (NEWSYNC) {
        // wait only the PREVIOUS iter's loads (fill `cur`); this iter's 4 stay in flight
        asm volatile("s_waitcnt vmcnt(4)" ::: "memory");
      }
    } else if constexpr (NEWSYNC) {
      asm volatile("s_waitcnt vmcnt(0)" ::: "memory");
    }
    if constexpr (NEWSYNC) {
      asm volatile("s_barrier" ::: "memory");   // RAW: cur visible to all waves
    }
    bf16x8 af[MF], bfr[4];
    #pragma unroll
    for (int m = 0; m < MF; ++m)
      af[m] = *(const bf16x8*)&sA[cur][(wmBase + m * 16 + lr) * 32 + kg * 8];
    #pragma unroll
    for (int n = 0; n < 4; ++n)
      bfr[n] = *(const bf16x8*)&sB[cur][(wnBase + n * 16 + lr) * 32 + kg * 8];
    #pragma unroll
    for (int m = 0; m < MF; ++m)
      #pragma unroll
      for (int n = 0; n < 4; ++n)
        acc[m][n] = __builtin_amdgcn_mfma_f32_16x16x32_bf16(af[m], bfr[n], acc[m][n], 0, 0, 0);
    if constexpr (NEWSYNC) {
      asm volatile("s_barrier" ::: "memory");   // WAR: all reads of cur done before overwrite
    } else {
      __syncthreads();
    }
  }

  // epilogue: C layout col=lane&15, row=(lane>>4)*4+reg
  #pragma unroll
  for (int m = 0; m < MF; ++m) {
    #pragma unroll
    for (int n = 0; n < 4; ++n) {
      int gc = by * TN + wnBase + n * 16 + lr;
      #pragma unroll
      for (int r = 0; r < 4; ++r) {
        int row = bx * TM + wmBase + m * 16 + kg * 4 + r;
        float v = acc[m][n][r];
        if constexpr (EPI == EPI_QKV) {
          const int which = by >> 3;           // 0=Q 1=K 2=V (block-uniform)
          const int wcol = gc & 1023;
          int bq = row >> 10, li = row & 1023, hh = wcol >> 6, d = wcol & 63;
          if (which == 0) {
            float y = (v + bias[wcol]) * scale;
            bf16* base = outB + ((size_t)(bq * NH_ + hh) * SEQ_ + li) * 128 + d;
            bf16 hi = (bf16)y, lo = (bf16)(y - (float)hi);
            base[0] = hi; base[64] = lo;
          } else if (which == 1) {
            float y = v + bias2[wcol];
            bf16* base = o2 + ((size_t)(bq * NH_ + hh) * SEQ_ + li) * 128 + d;
            bf16 hi = (bf16)y, lo = (bf16)(y - (float)hi);
            base[0] = hi; base[64] = lo;
          } else {
            float y = v + bias3[wcol];
            bf16* base = o3 + ((size_t)(bq * NH_ + hh) * HD_ + d) * 2048 + li;
            bf16 hi = (bf16)y, lo = (bf16)(y - (float)hi);
            base[0] = hi; base[1024] = lo;
          }
        } else if constexpr (EPI == EPI_OPROJ) {
          // fp32 split-K partial (bias+resid added in k_ln1gate)
          outF[((size_t)kz * 4096 + row) * 1024 + gc] = v;
        } else if constexpr (EPI == EPI_FF1) {
          float y = v + (expertBlk ? bias2[e * 4096 + gc] : bias[gc]);
          outB[(size_t)row * 4096 + gc] = (bf16)gelu_f(y);
        } else if constexpr (EPI == EPI_FF2) {
          // bf16 partial per K-chunk; bias added in k_final reduce
          o2[((size_t)kz * 8704 + row) * 1024 + gc] = (bf16)v;
        }
      }
    }
  }
}

// ============================ flash attention (swapped-QK^T, 32x32 MFMA) ============================
// 4 waves/block, each wave owns 32 queries of one (b,h); 512 blocks.
// S^T = K·Q^T via mfma_f32_32x32x16_bf16: C col=lane&31=QUERY, row=key -> softmax per-lane scalar
// state, row reduce = 15 in-reg ops + one shfl_xor(32). P stays in registers (bf16 hi/lo packs,
// redistributed for the PV B-operand with 8 shfl_xor(32)). PV computed transposed: O^T = V^T·P^T.
// K,V staged to double-buffered LDS. LDS = 32KB. s_setprio(1) wraps MFMA clusters (T5).
__global__ __launch_bounds__(256)
void k_attn(const bf16* __restrict__ q2, const bf16* __restrict__ k2,
            const bf16* __restrict__ vT2, const float* __restrict__ mask,
            const float* __restrict__ lhm, bf16* __restrict__ ctx2)
{
  // XCD swizzle: 512 blocks, 8 XCDs -> same-bh blocks land on one XCD's L2.
  const int blk = (blockIdx.x & 7) * 64 + (blockIdx.x >> 3);
  const int bh = blk >> 3, qb = blk & 7;
  const int tid = threadIdx.x;
  const int w = tid >> 6, lane = tid & 63;
  const int lq = lane & 31, hi = lane >> 5;
  const int b = bh >> 4, h = bh & 15;
  const int q0 = qb * 128 + w * 32;

  __shared__ __align__(16) bf16 sK[2][4096];   // 32 keys x [hi64|lo64] (chunk-swizzled rows)
  __shared__ __align__(16) bf16 sV[2][4096];   // 64 d x [32 hi|32 lo] (chunk-swizzled rows)

  // Q fragments (B-operand): lane holds row q0+lq, d-elems (hi*8 + j) of each 16-slice
  const bf16* qp = q2 + ((size_t)bh * SEQ_ + q0 + lq) * 128;
  bf16x8 qh[4], ql[4];
  #pragma unroll
  for (int s = 0; s < 4; ++s) {
    qh[s] = *(const bf16x8*)(qp + s * 16 + hi * 8);
    ql[s] = *(const bf16x8*)(qp + 64 + s * 16 + hi * 8);
  }

  const bf16* kp = k2 + (size_t)bh * SEQ_ * 128;
  const bf16* vp = vT2 + (size_t)bh * HD_ * 2048;
  const float* mp = mask + ((size_t)b * SEQ_ + q0 + lq) * SEQ_;

  // cooperative stage of one 32-key tile (K 8KB + V 8KB), pre-swizzled source
  auto stage = [&](int buf, int kb) {
    #pragma unroll
    for (int i = 0; i < 2; ++i) {
      int c = i * 256 + w * 64 + lane;
      // K: 256B rows; chunk swizzle c' = c ^ ((c>>4)&7)
      int cs = c ^ ((c >> 4) & 7);
      __builtin_amdgcn_global_load_lds((const void*)(kp + (size_t)kb * 128 + cs * 8),
                                       (void*)&sK[buf][(size_t)(i * 256 + w * 64) * 8], 16, 0, 0);
      // V: 128B rows [d][8 parts]; part swizzle p' = p ^ (d&7)
      int d = c >> 3, p = (c & 7) ^ (d & 7);
      const bf16* vsrc = vp + (size_t)d * 2048 + (p < 4 ? kb + p * 8 : 1024 + kb + (p - 4) * 8);
      __builtin_amdgcn_global_load_lds((const void*)vsrc,
                                       (void*)&sV[buf][(size_t)(i * 256 + w * 64) * 8], 16, 0, 0);
    }
  };

  float m_run = -1e30f, l_run = 0.f;
  f32x16 ot[2] = {};

  // mask prefetch: lane's query row, 16 keys at {8*r4 + 4*hi + 0..3}
  float4 mreg[4];
  #pragma unroll
  for (int r4 = 0; r4 < 4; ++r4)
    mreg[r4] = *(const float4*)(mp + 8 * r4 + 4 * hi);

  stage(0, 0);
  __syncthreads();

  for (int kc = 0; kc < SEQ_ / 32; ++kc) {
    const int kb = kc * 32;
    const int cur = kc & 1;
    if (kc + 1 < SEQ_ / 32) stage(cur ^ 1, kb + 32);

    const char* kbase = (const char*)sK[cur];
    const char* vbase = (const char*)sV[cur];

    // ---- QK^T (S^T): A = K rows, B = Q regs ----
    f32x16 st = {};
    __builtin_amdgcn_s_setprio(1);
    #pragma unroll
    for (int s = 0; s < 4; ++s) {
      int gh = s * 2 + hi, gl = 8 + s * 2 + hi;
      bf16x8 kh = *(const bf16x8*)(kbase + lq * 256 + ((gh ^ (lq & 7)) << 4));
      bf16x8 kl = *(const bf16x8*)(kbase + lq * 256 + ((gl ^ (lq & 7)) << 4));
      st = __builtin_amdgcn_mfma_f32_32x32x16_bf16(kh, qh[s], st, 0, 0, 0);
      st = __builtin_amdgcn_mfma_f32_32x32x16_bf16(kh, ql[s], st, 0, 0, 0);
      st = __builtin_amdgcn_mfma_f32_32x32x16_bf16(kl, qh[s], st, 0, 0, 0);
    }
    __builtin_amdgcn_s_setprio(0);
    // mask: st[reg] has key (reg&3)+8*(reg>>2)+4*hi
    #pragma unroll
    for (int reg = 0; reg < 16; ++reg)
      st[reg] = fmaf(((const float*)&mreg[reg >> 2])[reg & 3], L2E_, st[reg]);
    if (kc + 1 < SEQ_ / 32) {
      #pragma unroll
      for (int r4 = 0; r4 < 4; ++r4)
        mreg[r4] = *(const float4*)(mp + kb + 32 + 8 * r4 + 4 * hi);
    }

    // ---- softmax: per-lane (one query) ----
    float cm = st[0];
    #pragma unroll
    for (int reg = 1; reg < 16; ++reg) cm = fmaxf(cm, st[reg]);
    cm = fmaxf(cm, __shfl_xor(cm, 32, 64));
    float mnew = fmaxf(m_run, cm);
    float alpha = exp2f(m_run - mnew);
    float p[16];
    #pragma unroll
    for (int reg = 0; reg < 16; ++reg) p[reg] = exp2f(st[reg] - mnew);
    float rs = p[0];
    #pragma unroll
    for (int reg = 1; reg < 16; ++reg) rs += p[reg];
    rs += __shfl_xor(rs, 32, 64);
    l_run = l_run * alpha + rs; m_run = mnew;
    #pragma unroll
    for (int i = 0; i < 16; ++i) { ot[0][i] *= alpha; ot[1][i] *= alpha; }

    // ---- P -> bf16 hi/lo packs, redistribute for PV B-operand ----
    unsigned hA0 = pk2h(p[0], p[1]),  hA1 = pk2h(p[2], p[3]);
    unsigned hB0 = pk2h(p[4], p[5]),  hB1 = pk2h(p[6], p[7]);
    unsigned hC0 = pk2h(p[8], p[9]),  hC1 = pk2h(p[10], p[11]);
    unsigned hD0 = pk2h(p[12], p[13]), hD1 = pk2h(p[14], p[15]);
    unsigned lA0 = pk2l(p[0], p[1]),  lA1 = pk2l(p[2], p[3]);
    unsigned lB0 = pk2l(p[4], p[5]),  lB1 = pk2l(p[6], p[7]);
    unsigned lC0 = pk2l(p[8], p[9]),  lC1 = pk2l(p[10], p[11]);
    unsigned lD0 = pk2l(p[12], p[13]), lD1 = pk2l(p[14], p[15]);
    // exchange: hi=0 needs partner A, hi=1 needs partner B (slice0); C/D for slice1
    unsigned x0 = (unsigned)__shfl_xor((int)(hi ? hA0 : hB0), 32, 64);
    unsigned x1 = (unsigned)__shfl_xor((int)(hi ? hA1 : hB1), 32, 64);
    unsigned x2 = (unsigned)__shfl_xor((int)(hi ? hC0 : hD0), 32, 64);
    unsigned x3 = (unsigned)__shfl_xor((int)(hi ? hC1 : hD1), 32, 64);
    unsigned y0 = (unsigned)__shfl_xor((int)(hi ? lA0 : lB0), 32, 64);
    unsigned y1 = (unsigned)__shfl_xor((int)(hi ? lA1 : lB1), 32, 64);
    unsigned y2 = (unsigned)__shfl_xor((int)(hi ? lC0 : lD0), 32, 64);
    unsigned y3 = (unsigned)__shfl_xor((int)(hi ? lC1 : lD1), 32, 64);
    bf16x8 pb0h = hi ? mk8(x0, x1, hB0, hB1) : mk8(hA0, hA1, x0, x1);
    bf16x8 pb1h = hi ? mk8(x2, x3, hD0, hD1) : mk8(hC0, hC1, x2, x3);
    bf16x8 pb0l = hi ? mk8(y0, y1, lB0, lB1) : mk8(lA0, lA1, y0, y1);
    bf16x8 pb1l = hi ? mk8(y2, y3, lD0, lD1) : mk8(lC0, lC1, y2, y3);

    // ---- PV (O^T): A = V^T rows from LDS, B = P packs ----
    __builtin_amdgcn_s_setprio(1);
    #pragma unroll
    for (int ks = 0; ks < 2; ++ks) {
      bf16x8 pbh = ks ? pb1h : pb0h;
      bf16x8 pbl = ks ? pb1l : pb0l;
      #pragma unroll
      for (int t = 0; t < 2; ++t) {
        int row = t * 32 + lq;
        int gh = ks * 2 + hi, gl = 4 + ks * 2 + hi;
        bf16x8 vh = *(const bf16x8*)(vbase + row * 128 + ((gh ^ (row & 7)) << 4));
        bf16x8 vl = *(const bf16x8*)(vbase + row * 128 + ((gl ^ (row & 7)) << 4));
        ot[t] = __builtin_amdgcn_mfma_f32_32x32x16_bf16(vh, pbh, ot[t], 0, 0, 0);
        ot[t] = __builtin_amdgcn_mfma_f32_32x32x16_bf16(vh, pbl, ot[t], 0, 0, 0);
        ot[t] = __builtin_amdgcn_mfma_f32_32x32x16_bf16(vl, pbh, ot[t], 0, 0, 0);
      }
    }
    __builtin_amdgcn_s_setprio(0);

    __syncthreads();   // drains staging (vmcnt) + LDS reads before buffer swap
  }

  // ---- epilogue: O^T col=lane&31=query (in-lane l_run), row=d ----
  const float rln = lhm[h] / l_run;
  bf16* base = ctx2 + ((size_t)b * SEQ_ + q0 + lq) * 2048;
  #pragma unroll
  for (int t = 0; t < 2; ++t)
    #pragma unroll
    for (int reg = 0; reg < 16; ++reg) {
      int d = (reg & 3) + 8 * (reg >> 2) + 4 * hi + 32 * t;
      int col = h * HD_ + d;
      float y = ot[t][reg] * rln;
      bf16 yh = (bf16)y, yl = (bf16)(y - (float)yh);
      base[col] = yh; base[1024 + col] = yl;
    }
}

// ============================ layernorm+gate / route / final ============================
DEV float blockReduceSum(float v, int tid, float* sm)
{
  #pragma unroll
  for (int d = 1; d < 64; d <<= 1) v += __shfl_xor(v, d, 64);
  if ((tid & 63) == 0) sm[tid >> 6] = v;
  __syncthreads();
  float r = sm[0] + sm[1] + sm[2] + sm[3];
  __syncthreads();
  return r;
}

// OPROJ-reduce + LN1 + gate fused: z = hidden + P0 + P1 + ob; h = LN(z); gate from h.
__global__ __launch_bounds__(256)
void k_ln1gate(const float* __restrict__ resid, const float* __restrict__ Pp, const float* __restrict__ ob,
               const float* __restrict__ gam, const float* __restrict__ bet,
               const float* __restrict__ gw, const float* __restrict__ gb, const int* __restrict__ idxes,
               float* __restrict__ h, bf16* __restrict__ hb,
               float* __restrict__ gv, int* __restrict__ gi)
{
  __shared__ float sm[4];
  __shared__ float red[4][4];
  int t = blockIdx.x, tid = threadIdx.x;
  constexpr size_t CH = 4096ull * 1024ull;
  float4 rv = *(const float4*)(resid + (size_t)t * 1024 + tid * 4);
  float4 p0 = *(const float4*)(Pp + (size_t)t * 1024 + tid * 4);
  float4 p1 = *(const float4*)(Pp + CH + (size_t)t * 1024 + tid * 4);
  float4 bo = *(const float4*)(ob + tid * 4);
  float z0 = rv.x + p0.x + p1.x + bo.x;
  float z1 = rv.y + p0.y + p1.y + bo.y;
  float z2 = rv.z + p0.z + p1.z + bo.z;
  float z3 = rv.w + p0.w + p1.w + bo.w;
  float mean = blockReduceSum(z0 + z1 + z2 + z3, tid, sm) * (1.f / 1024.f);
  float d0 = z0 - mean, d1 = z1 - mean, d2 = z2 - mean, d3 = z3 - mean;
  float var = blockReduceSum(d0*d0 + d1*d1 + d2*d2 + d3*d3, tid, sm) * (1.f / 1024.f);
  float inv = rsqrtf(var + 1e-5f);
  float4 g4 = *(const float4*)(gam + tid * 4);
  float4 b4 = *(const float4*)(bet + tid * 4);
  float y0 = d0 * inv * g4.x + b4.x, y1 = d1 * inv * g4.y + b4.y;
  float y2 = d2 * inv * g4.z + b4.z, y3 = d3 * inv * g4.w + b4.w;
  float4 yo; yo.x = y0; yo.y = y1; yo.z = y2; yo.w = y3;
  *(float4*)(h + (size_t)t * 1024 + tid * 4) = yo;
  bf16x4v hv; hv[0] = (bf16)y0; hv[1] = (bf16)y1; hv[2] = (bf16)y2; hv[3] = (bf16)y3;
  *(bf16x4v*)(hb + (size_t)t * 1024 + tid * 4) = hv;

  // ---- gate ----
  int ds = idxes[t >> 10];
  const float* wg = gw + (size_t)ds * 4096;
  float a[4];
  #pragma unroll
  for (int e = 0; e < 4; ++e) {
    float4 wv = *(const float4*)(wg + e * 1024 + tid * 4);
    a[e] = y0 * wv.x + y1 * wv.y + y2 * wv.z + y3 * wv.w;
  }
  int lane = tid & 63, wid = tid >> 6;
  #pragma unroll
  for (int e = 0; e < 4; ++e) {
    float vv = a[e];
    #pragma unroll
    for (int d = 1; d < 64; d <<= 1) vv += __shfl_xor(vv, d, 64);
    if (lane == 0) red[wid][e] = vv;
  }
  __syncthreads();
  if (tid == 0) {
    float lg[4];
    #pragma unroll
    for (int e = 0; e < 4; ++e) lg[e] = red[0][e] + red[1][e] + red[2][e] + red[3][e] + gb[ds * 4 + e];
    int best = 0; float bv = lg[0];
    #pragma unroll
    for (int e = 1; e < 4; ++e) if (lg[e] > bv) { bv = lg[e]; best = e; }
    float se = 0.f;
    #pragma unroll
    for (int e = 0; e < 4; ++e) se += expf(lg[e] - bv);
    gv[t] = 1.f / se;
    gi[t] = best;
  }
}

// Single-block routing: count -> segments -> scatter (+ inverse map token->expert row).
__global__ __launch_bounds__(1024)
void k_route_all(const int* __restrict__ gi, int* __restrict__ meta,
                 int* __restrict__ perm, int* __restrict__ inv)
{
  __shared__ int cnt[4], seg[5], cur[4];
  int tid = threadIdx.x;
  if (tid < 4) { cnt[tid] = 0; cur[tid] = 0; }
  __syncthreads();
  #pragma unroll
  for (int k = 0; k < 4; ++k) atomicAdd(&cnt[gi[tid + k * 1024]], 1);
  #pragma unroll
  for (int k = 0; k < 5; ++k) { int i = tid + k * 1024; if (i < 4608) perm[i] = -1; }
  __syncthreads();
  if (tid == 0) {
    int s = 0;
    #pragma unroll
    for (int e = 0; e < 4; ++e) { seg[e] = s; s += (cnt[e] + 127) & ~127; }
    seg[4] = s;
    #pragma unroll
    for (int e = 0; e < 5; ++e) meta[8 + e] = seg[e];
  }
  __syncthreads();
  #pragma unroll
  for (int k = 0; k < 4; ++k) {
    int t = tid + k * 1024;
    int e = gi[t];
    int p = atomicAdd(&cur[e], 1);
    int rowp = seg[e] + p;
    perm[rowp] = t;
    inv[t] = rowp;
  }
}

// Final: reduce 2 split-K partials x (shared row + expert row) + fc2b, then LN2 * gate.
__global__ __launch_bounds__(256)
void k_final(const float* __restrict__ h, const bf16* __restrict__ P,
             const float* __restrict__ b2, const float* __restrict__ gam,
             const float* __restrict__ bet, const float* __restrict__ gv,
             const int* __restrict__ inv, float* __restrict__ out)
{
  __shared__ float sm[4];
  int t = blockIdx.x, tid = threadIdx.x;
  constexpr size_t CH = 8704ull * 1024ull;
  int er = 4096 + inv[t];
  bf16x4v q0 = *(const bf16x4v*)(P + (size_t)t * 1024 + tid * 4);
  bf16x4v q1 = *(const bf16x4v*)(P + CH + (size_t)t * 1024 + tid * 4);
  bf16x4v q2 = *(const bf16x4v*)(P + (size_t)er * 1024 + tid * 4);
  bf16x4v q3 = *(const bf16x4v*)(P + CH + (size_t)er * 1024 + tid * 4);
  float4 a = *(const float4*)(h + (size_t)t * 1024 + tid * 4);
  float4 bb = *(const float4*)(b2 + tid * 4);
  float z0 = a.x + (float)q0[0] + (float)q1[0] + (float)q2[0] + (float)q3[0] + bb.x;
  float z1 = a.y + (float)q0[1] + (float)q1[1] + (float)q2[1] + (float)q3[1] + bb.y;
  float z2 = a.z + (float)q0[2] + (float)q1[2] + (float)q2[2] + (float)q3[2] + bb.z;
  float z3 = a.w + (float)q0[3] + (float)q1[3] + (float)q2[3] + (float)q3[3] + bb.w;
  float mean = blockReduceSum(z0 + z1 + z2 + z3, tid, sm) * (1.f / 1024.f);
  float d0 = z0 - mean, d1 = z1 - mean, d2 = z2 - mean, d3 = z3 - mean;
  float var = blockReduceSum(d0*d0 + d1*d1 + d2*d2 + d3*d3, tid, sm) * (1.f / 1024.f);
  float invd = rsqrtf(var + 1e-5f);
  float4 g4 = *(const float4*)(gam + tid * 4);
  float4 b4 = *(const float4*)(bet + tid * 4);
  float gval = gv[t];
  float4 r;
  r.x = gval * (d0 * invd * g4.x + b4.x);
  r.y = gval * (d1 * invd * g4.y + b4.y);
  r.z = gval * (d2 * invd * g4.z + b4.z);
  r.w = gval * (d3 * invd * g4.w + b4.w);
  *(float4*)(out + (size_t)t * 1024 + tid * 4) = r;
}

// ============================ host ============================
extern "C" void kernel_launch(void* const* d_in, const int* in_sizes, int n_in,
                              void* d_out, int out_size, void* d_ws, size_t ws_size,
                              hipStream_t stream)
{
  const float* hidden = (const float*)d_in[0];
  const float* mask   = (const float*)d_in[1];
  const float* lhm    = (const float*)d_in[2];
  const int*   idxes  = (const int*)d_in[3];
  const float* qw = (const float*)d_in[4];
  const float* kw = (const float*)d_in[5];
  const float* vw = (const float*)d_in[6];
  const float* ow = (const float*)d_in[7];
  const float* fc1w  = (const float*)d_in[8];
  const float* fc2w  = (const float*)d_in[9];
  const float* efc1w = (const float*)d_in[10];
  const float* efc2w = (const float*)d_in[11];
  const float* gatew = (const float*)d_in[12];
  const float* qb = (const float*)d_in[13];
  const float* kb = (const float*)d_in[14];
  const float* vb = (const float*)d_in[15];
  const float* ob = (const float*)d_in[16];
  const float* fc1b  = (const float*)d_in[17];
  const float* fc2b  = (const float*)d_in[18];
  const float* efc1b = (const float*)d_in[19];
  const float* gateb = (const float*)d_in[20];
  const float* ln1g = (const float*)d_in[21];
  const float* ln1b = (const float*)d_in[22];
  const float* ln2g = (const float*)d_in[23];
  const float* ln2b = (const float*)d_in[24];
  float* out = (float*)d_out;
  char* ws = (char*)d_ws;

  constexpr size_t MB = 1024ull * 1024ull;
  // persistent
  constexpr size_t O_H    = 0;                     // fp32 h [4096][1024]
  constexpr size_t O_HBF  = O_H + 16 * MB;         // bf16 h
  constexpr size_t O_GV   = O_HBF + 8 * MB;
  constexpr size_t O_GI   = O_GV + 16 * 1024;
  constexpr size_t O_PERM = O_GI + 16 * 1024;      // 4608 ints
  constexpr size_t O_META = O_PERM + 18432;
  constexpr size_t O_INV  = O_META + 256;          // 4096 ints
  constexpr size_t O_U    = (O_INV + 16384 + 255) & ~255ull;
  // attention-phase overlay (contiguous split-bf16 block: X2|WQ2|WK2|WV2|WO2)
  constexpr size_t O_X2   = O_U;                   // [4096][2048] bf16
  constexpr size_t O_WQ2  = O_X2 + 16 * MB;        // [3072][2048]: Q,K,V weights contiguous
  constexpr size_t O_Q2   = O_WQ2 + 16 * MB;       // [B*NH*L][128]
  constexpr size_t O_K2   = O_Q2 + 16 * MB;
  constexpr size_t O_VT2  = O_K2 + 16 * MB;        // [B*NH*HD][2048]
  constexpr size_t O_CTX2 = O_VT2 + 16 * MB;       // [4096][2048]
  constexpr size_t O_HPRE = O_CTX2 + 16 * MB;      // fp32 2 x [4096][1024] OPROJ split-K partials
  constexpr size_t O_WO2  = O_WQ2 + 12 * MB;       // ow rows inside the contiguous block
  // MoE-phase overlay (same region — attn buffers dead by then)
  constexpr size_t O_W1B  = O_U;                   // [fc1|efc1x4|fc2|efc2x4] contiguous 80 MB bf16
  constexpr size_t O_WE1B = O_W1B + 8 * MB;
  constexpr size_t O_W2B  = O_WE1B + 32 * MB;
  constexpr size_t O_WE2B = O_W2B + 8 * MB;
  constexpr size_t O_HHS  = O_WE2B + 32 * MB;      // [4096][4096] bf16 (shared)  — contiguous with
  constexpr size_t O_HHE  = O_HHS + 32 * MB;       // [4608][4096] bf16 (expert)  — HHS (rows 4096+)
  constexpr size_t O_P    = O_HHE + 36 * MB;       // 2 x [8704][1024] bf16 split-K partials (34 MB)
  (void)ws_size; (void)in_sizes; (void)n_in; (void)out_size;

  dim3 blk(256);
  // ---- phase 1: attention-path conversions (hi|lo split, ONE launch, contiguous dst) ----
  k_cvt_split_all<<<8192, 256, 0, stream>>>(hidden, qw, kw, vw, ow, (bf16*)(ws + O_X2));

  // ---- phase 2: fused QKV projection (N=3072, 768 blocks) ----
  const float qscale = 0.125f * L2E_;   // fold softmax scale and log2e into Q
  k_gemm<EPI_QKV, true, 128, 128, true><<<dim3(32, 24), blk, 0, stream>>>(
      (bf16*)(ws + O_X2), (bf16*)(ws + O_WQ2), qb, kb, vb, nullptr,
      nullptr, (bf16*)(ws + O_Q2), (bf16*)(ws + O_K2), (bf16*)(ws + O_VT2),
      nullptr, nullptr, 2048, 96, qscale);

  // ---- phase 3: attention (swapped-QK^T 32x32 structure, 512 blocks) ----
  k_attn<<<512, 256, 0, stream>>>((bf16*)(ws + O_Q2), (bf16*)(ws + O_K2), (bf16*)(ws + O_VT2),
                                  mask, lhm, (bf16*)(ws + O_CTX2));

  // ---- phase 4: output projection (split-K x2, fp32 partials), then fused reduce+LN1+gate ----
  k_gemm<EPI_OPROJ, true, 128, 64, true><<<dim3(32, 16, 2), blk, 0, stream>>>(
      (bf16*)(ws + O_CTX2), (bf16*)(ws + O_WO2), nullptr, nullptr, nullptr, nullptr,
      (float*)(ws + O_HPRE), nullptr, nullptr, nullptr, nullptr, nullptr, 2048, 48, 1.0f);
  k_ln1gate<<<4096, 256, 0, stream>>>(hidden, (float*)(ws + O_HPRE), ob, ln1g, ln1b,
                                      gatew, gateb, idxes,
                                      (float*)(ws + O_H), (bf16*)(ws + O_HBF),
                                      (float*)(ws + O_GV), (int*)(ws + O_GI));

  // ---- phase 5: MoE weight conversion (ONE launch), routing (ONE block) ----
  k_cvt4<<<40960, 256, 0, stream>>>(fc1w, efc1w, fc2w, efc2w, (bf16*)(ws + O_W1B));
  k_route_all<<<1, 1024, 0, stream>>>((int*)(ws + O_GI), (int*)(ws + O_META),
                                      (int*)(ws + O_PERM), (int*)(ws + O_INV));

  // ---- phase 6: fused shared+expert FFN (NEWSYNC counted-vmcnt pipeline) ----
  // FF1: single launch, TM=128, plain 2D grid (68,32)
  k_gemm<EPI_FF1, false, 128, 128, true><<<dim3(68, 32), blk, 0, stream>>>(
      (bf16*)(ws + O_HBF), (bf16*)(ws + O_W1B), fc1b, efc1b, nullptr, nullptr,
      nullptr, (bf16*)(ws + O_HHS), nullptr, nullptr,
      (int*)(ws + O_PERM), (int*)(ws + O_META) + 8, 1024, 32, 1.0f);
  // FF2: split-K x2 into bf16 partials — 1088 blocks, A-grouped per XCD
  k_gemm<EPI_FF2, false, 128, 128, true><<<dim3(1088), blk, 0, stream>>>(
      (bf16*)(ws + O_HHS), (bf16*)(ws + O_W2B), nullptr, nullptr, nullptr, nullptr,
      nullptr, nullptr, (bf16*)(ws + O_P), nullptr,
      nullptr, (int*)(ws + O_META) + 8, 4096, 64, 1.0f);

  // ---- phase 7: final reduce + LN2 * gate_value ----
  k_final<<<4096, 256, 0, stream>>>((float*)(ws + O_H), (bf16*)(ws + O_P), fc2b, ln2g, ln2b,
                                    (float*)(ws + O_GV), (int*)(ws + O_INV), out);
}

// Round 27
// 518.463 us; speedup vs baseline: 1.0711x; 1.0428x over previous
//
#include <hip/hip_runtime.h>
#include <cstdint>
#include <cstddef>

#define DEV __device__ __forceinline__

typedef __bf16 bf16;
typedef __bf16 bf16x8 __attribute__((ext_vector_type(8)));
typedef __bf16 bf16x4v __attribute__((ext_vector_type(4)));
typedef float  f32x4  __attribute__((ext_vector_type(4)));
typedef float  f32x16 __attribute__((ext_vector_type(16)));
typedef unsigned int uint4v __attribute__((ext_vector_type(4)));

static constexpr int D_   = 1024;
static constexpr int FFN_ = 4096;
static constexpr int NH_  = 16;
static constexpr int HD_  = 64;
static constexpr int SEQ_ = 1024;
static constexpr int T_   = 4 * SEQ_;   // 4096 tokens
static constexpr float L2E_ = 1.4426950408889634f;

// tanh-form GELU via exp2+rcp (~6 VALU ops vs ~22 for erff; |err|<=1e-3, subdominant to bf16 hh cast)
DEV float gelu_f(float x) {
  float g2 = x * fmaf(-0.102944f, x * x, -2.302212f);   // -log2e*1.5957691*(x+0.044715x^3)/x
  return x * __builtin_amdgcn_rcpf(1.f + exp2f(g2));
}

DEV unsigned pk2h(float a, float b) {
  unsigned ua = __builtin_bit_cast(unsigned short, (bf16)a);
  unsigned ub = __builtin_bit_cast(unsigned short, (bf16)b);
  return ua | (ub << 16);
}
DEV unsigned pk2l(float a, float b) {
  bf16 ha = (bf16)a, hb = (bf16)b;
  unsigned ua = __builtin_bit_cast(unsigned short, (bf16)(a - (float)ha));
  unsigned ub = __builtin_bit_cast(unsigned short, (bf16)(b - (float)hb));
  return ua | (ub << 16);
}
DEV bf16x8 mk8(unsigned w0, unsigned w1, unsigned w2, unsigned w3) {
  uint4v v = {w0, w1, w2, w3};
  return __builtin_bit_cast(bf16x8, v);
}

// ============================ conversions (merged) ============================
// MoE weights: fc1(4M) | efc1(16M) | fc2(4M) | efc2(16M) elems -> ONE contiguous bf16 dst.
__global__ __launch_bounds__(256) void k_cvt4(const float* __restrict__ a, const float* __restrict__ b,
                                              const float* __restrict__ c, const float* __restrict__ d,
                                              bf16* __restrict__ dst)
{
  size_t i = ((size_t)blockIdx.x * 256 + threadIdx.x) * 4;
  constexpr size_t M1 = 4ull << 20, M2 = 20ull << 20, M3 = 24ull << 20, M4 = 40ull << 20;
  const float* src; size_t si;
  if (i < M1)      { src = a; si = i; }
  else if (i < M2) { src = b; si = i - M1; }
  else if (i < M3) { src = c; si = i - M2; }
  else if (i < M4) { src = d; si = i - M3; }
  else return;
  float4 v = *(const float4*)(src + si);
  bf16x4v o;
  o[0] = (bf16)v.x; o[1] = (bf16)v.y; o[2] = (bf16)v.z; o[3] = (bf16)v.w;
  *(bf16x4v*)(dst + i) = o;
}

// Attention path: hidden(4M) | qw(1M) | kw(1M) | vw(1M) | ow(1M) elems, each row [1024] fp32
// -> contiguous bf16 [8192 rows][2048] hi|lo split at single dst base.
__global__ __launch_bounds__(256) void k_cvt_split_all(
    const float* __restrict__ h, const float* __restrict__ qw, const float* __restrict__ kw,
    const float* __restrict__ vw, const float* __restrict__ ow, bf16* __restrict__ out)
{
  int i = (blockIdx.x * 256 + threadIdx.x) * 4;
  if (i >= (8 << 20)) return;
  int seg = i >> 20;
  const float* src; int si;
  if (seg < 4)       { src = h;  si = i; }
  else if (seg == 4) { src = qw; si = i - (4 << 20); }
  else if (seg == 5) { src = kw; si = i - (5 << 20); }
  else if (seg == 6) { src = vw; si = i - (6 << 20); }
  else               { src = ow; si = i - (7 << 20); }
  float4 v = *(const float4*)(src + si);
  int r = i >> 10, c = i & 1023;
  bf16* base = out + (size_t)r * 2048 + c;
  float xs[4] = {v.x, v.y, v.z, v.w};
  #pragma unroll
  for (int j = 0; j < 4; ++j) {
    float x = xs[j];
    bf16 hi = (bf16)x;
    bf16 lo = (bf16)(x - (float)hi);
    base[j]        = hi;
    base[1024 + j] = lo;
  }
}

// ============================ GEMM (C = A @ B^T), TMxTN tile, BK=32 ============================
// SPLIT: A,B are [rows][2048] hi|lo; virtual K=3072: kt 0..31:(Ah,Bh) 32..63:(Al,Bh) 64..95:(Ah,Bl)
// FUSED (FF1/FF2): bx<SBX = shared branch; bx>=SBX = expert branch (weight e+1, row offset 4096).
// OPROJ/FF2 split-K x2: chunk z handles kt [z*nk,(z+1)*nk); disjoint partials, no atomics.
// FF2 XCD swizzle: 1D 1088 blocks, work=(gid&7)*136+(gid>>3), by-fastest -> same-XCD share A tiles.
// NEWSYNC (all GEMMs): counted-vmcnt 2-barrier sync — issue stage early, wait only the PREVIOUS
// iter's loads (vmcnt(LPS), LPS = loads-per-stage: 4 for TN=128, 3 for OPROJ's TN=64 — the
// LPS-correct count closes a latent race where vmcnt(4) left OPROJ's previous B-load unordered),
// raw s_barrier before reads (RAW) and after MFMA (WAR).
// FINAL configuration (session best, 522.0us R22). Dispositioned levers: HBM traffic (R16/R18:
// FETCH 217->86MB, dur flat), occupancy/tile growth (R11/R14/R16/R19: all cliff), LDS conflicts
// (R23: 8.9M->0, dur flat), depth-2 prefetch (R24: neutral), attn+cvt block fusion (R25: -33us,
// wave-slot contention), 256^2 2-phase (analysis: 1 blk/CU tail -> 512 TF < 634, regression).
// GEMMs are at the 2-barrier 128^2 family's structural ceiling.
enum { EPI_QKV = 0, EPI_OPROJ, EPI_FF1, EPI_FF2 };

DEV int map_akt(int kt, bool split) { return split ? (kt < 64 ? kt : kt - 64) : kt; }
DEV int map_bkt(int kt, bool split) { return split ? (kt < 32 ? kt : kt - 32) : kt; }

template<int EPI, bool SPLIT, int TM, int TN, bool NEWSYNC>
__global__ __launch_bounds__(256)
void k_gemm(const bf16* __restrict__ A, const bf16* __restrict__ Bw,
            const float* __restrict__ bias, const float* __restrict__ bias2,
            const float* __restrict__ bias3, const float* __restrict__ resid,
            float* __restrict__ outF, bf16* __restrict__ outB,
            bf16* __restrict__ o2, bf16* __restrict__ o3,
            const int* __restrict__ perm, const int* __restrict__ seg,
            int Kphys, int nk, float scale)
{
  constexpr bool FUSED = (EPI == EPI_FF1 || EPI == EPI_FF2);
  constexpr int  NCOL  = (EPI == EPI_FF1) ? 4096 : 1024;   // expert weight rows
  constexpr int  SBX   = 4096 / TM;                        // shared-branch block count
  constexpr int  MF    = (TN == 128) ? (TM / 32) : (TM / 64);
  constexpr int  AISS  = TM / 64;
  constexpr int  BISS  = TN / 64;
  constexpr int  LPS   = AISS + BISS;                      // loads per stage (vmcnt count)

  __shared__ __align__(16) bf16 sA[2][TM * 32];
  __shared__ __align__(16) bf16 sB[2][TN * 32];

  const int tid  = threadIdx.x;
  const int lane = tid & 63;
  const int w    = tid >> 6;
  const int lr   = lane & 15, kg = lane >> 4;
  const int wmBase = (TN == 128) ? (w >> 1) * (TM / 2) : w * (TM / 4);
  const int wnBase = (TN == 128) ? (w & 1) * 64 : 0;

  int bx, by, kz = 0;
  if constexpr (EPI == EPI_FF2) {
    int wk = (blockIdx.x & 7) * 136 + (blockIdx.x >> 3);
    kz = wk / 544; int r2 = wk % 544;
    bx = r2 >> 3; by = r2 & 7;                             // by-fastest: share A tiles
  } else {
    bx = blockIdx.x; by = blockIdx.y; kz = blockIdx.z;
  }
  const int ktBase = (EPI == EPI_OPROJ || EPI == EPI_FF2) ? kz * nk : 0;

  const bool expertBlk = FUSED && (bx >= SBX);
  int e = 0;
  if (FUSED && expertBlk) { int r0 = (bx - SBX) * TM; while (e < 3 && r0 >= seg[e + 1]) e++; }
  const bf16* Bp = Bw + (expertBlk ? (size_t)(e + 1) * NCOL * Kphys : 0);

  const bf16* aSrc[AISS]; const bf16* bSrc[BISS];
  #pragma unroll
  for (int i = 0; i < AISS; ++i) {
    int c = tid + i * 256;
    int koff = (c & 3) * 8;
    if (EPI == EPI_FF1 && expertBlk) {
      int pr = perm[(bx - SBX) * TM + (c >> 2)];
      aSrc[i] = A + (size_t)(pr < 0 ? 0 : pr) * Kphys + koff;
    } else {
      aSrc[i] = A + (size_t)(bx * TM + (c >> 2)) * Kphys + koff;
    }
  }
  #pragma unroll
  for (int i = 0; i < BISS; ++i) {
    int c = tid + i * 256;
    int koff = (c & 3) * 8;
    bSrc[i] = Bp + (size_t)(by * TN + (c >> 2)) * Kphys + koff;
  }

  f32x4 acc[MF][4] = {};

  {
    int ak0 = map_akt(ktBase, SPLIT), bk0 = map_bkt(ktBase, SPLIT);
    #pragma unroll
    for (int i = 0; i < AISS; ++i)
      __builtin_amdgcn_global_load_lds((const void*)(aSrc[i] + (size_t)ak0 * 32),
                                       (void*)((char*)sA[0] + (tid + i * 256) * 16), 16, 0, 0);
    #pragma unroll
    for (int i = 0; i < BISS; ++i)
      __builtin_amdgcn_global_load_lds((const void*)(bSrc[i] + (size_t)bk0 * 32),
                                       (void*)((char*)sB[0] + (tid + i * 256) * 16), 16, 0, 0);
  }
  __syncthreads();

  for (int kt = 0; kt < nk; ++kt) {
    const int cur = kt & 1;
    if (kt + 1 < nk) {
      int ak = map_akt(ktBase + kt + 1, SPLIT), bk = map_bkt(ktBase + kt + 1, SPLIT);
      #pragma unroll
      for (int i = 0; i < AISS; ++i)
        __builtin_amdgcn_global_load_lds((const void*)(aSrc[i] + (size_t)ak * 32),
                                         (void*)((char*)sA[cur ^ 1] + (tid + i * 256) * 16), 16, 0, 0);
      #pragma unroll
      for (int i = 0; i < BISS; ++i)
        __builtin_amdgcn_global_load_lds((const void*)(bSrc[i] + (size_t)bk * 32),
                                         (void*)((char*)sB[cur ^ 1] + (tid + i * 256) * 16), 16, 0, 0);
      if constexpr (NEWSYNC) {
        // wait only the PREVIOUS iter's LPS loads (fill `cur`); this iter's LPS stay in flight
        if constexpr (LPS == 4) asm volatile("s_waitcnt vmcnt(4)" ::: "memory");
        else                    asm volatile("s_waitcnt vmcnt(3)" ::: "memory");
      }
    } else if constexpr (NEWSYNC) {
      asm volatile("s_waitcnt vmcnt(0)" ::: "memory");
    }
    if constexpr (NEWSYNC) {
      asm volatile("s_barrier" ::: "memory");   // RAW: cur visible to all waves
    }
    bf16x8 af[MF], bfr[4];
    #pragma unroll
    for (int m = 0; m < MF; ++m)
      af[m] = *(const bf16x8*)&sA[cur][(wmBase + m * 16 + lr) * 32 + kg * 8];
    #pragma unroll
    for (int n = 0; n < 4; ++n)
      bfr[n] = *(const bf16x8*)&sB[cur][(wnBase + n * 16 + lr) * 32 + kg * 8];
    #pragma unroll
    for (int m = 0; m < MF; ++m)
      #pragma unroll
      for (int n = 0; n < 4; ++n)
        acc[m][n] = __builtin_amdgcn_mfma_f32_16x16x32_bf16(af[m], bfr[n], acc[m][n], 0, 0, 0);
    if constexpr (NEWSYNC) {
      asm volatile("s_barrier" ::: "memory");   // WAR: all reads of cur done before overwrite
    } else {
      __syncthreads();
    }
  }

  // epilogue: C layout col=lane&15, row=(lane>>4)*4+reg
  #pragma unroll
  for (int m = 0; m < MF; ++m) {
    #pragma unroll
    for (int n = 0; n < 4; ++n) {
      int gc = by * TN + wnBase + n * 16 + lr;
      #pragma unroll
      for (int r = 0; r < 4; ++r) {
        int row = bx * TM + wmBase + m * 16 + kg * 4 + r;
        float v = acc[m][n][r];
        if constexpr (EPI == EPI_QKV) {
          const int which = by >> 3;           // 0=Q 1=K 2=V (block-uniform)
          const int wcol = gc & 1023;
          int bq = row >> 10, li = row & 1023, hh = wcol >> 6, d = wcol & 63;
          if (which == 0) {
            float y = (v + bias[wcol]) * scale;
            bf16* base = outB + ((size_t)(bq * NH_ + hh) * SEQ_ + li) * 128 + d;
            bf16 hi = (bf16)y, lo = (bf16)(y - (float)hi);
            base[0] = hi; base[64] = lo;
          } else if (which == 1) {
            float y = v + bias2[wcol];
            bf16* base = o2 + ((size_t)(bq * NH_ + hh) * SEQ_ + li) * 128 + d;
            bf16 hi = (bf16)y, lo = (bf16)(y - (float)hi);
            base[0] = hi; base[64] = lo;
          } else {
            float y = v + bias3[wcol];
            bf16* base = o3 + ((size_t)(bq * NH_ + hh) * HD_ + d) * 2048 + li;
            bf16 hi = (bf16)y, lo = (bf16)(y - (float)hi);
            base[0] = hi; base[1024] = lo;
          }
        } else if constexpr (EPI == EPI_OPROJ) {
          // fp32 split-K partial (bias+resid added in k_ln1gate)
          outF[((size_t)kz * 4096 + row) * 1024 + gc] = v;
        } else if constexpr (EPI == EPI_FF1) {
          float y = v + (expertBlk ? bias2[e * 4096 + gc] : bias[gc]);
          outB[(size_t)row * 4096 + gc] = (bf16)gelu_f(y);
        } else if constexpr (EPI == EPI_FF2) {
          // bf16 partial per K-chunk; bias added in k_final reduce
          o2[((size_t)kz * 8704 + row) * 1024 + gc] = (bf16)v;
        }
      }
    }
  }
}

// ============================ flash attention (swapped-QK^T, 32x32 MFMA) ============================
// 4 waves/block, each wave owns 32 queries of one (b,h); 512 blocks.
// S^T = K·Q^T via mfma_f32_32x32x16_bf16: C col=lane&31=QUERY, row=key -> softmax per-lane scalar
// state, row reduce = 15 in-reg ops + one shfl_xor(32). P stays in registers (bf16 hi/lo packs,
// redistributed for the PV B-operand with 8 shfl_xor(32)). PV computed transposed: O^T = V^T·P^T.
// K,V staged to double-buffered LDS. LDS = 32KB. s_setprio(1) wraps MFMA clusters (T5).
__global__ __launch_bounds__(256)
void k_attn(const bf16* __restrict__ q2, const bf16* __restrict__ k2,
            const bf16* __restrict__ vT2, const float* __restrict__ mask,
            const float* __restrict__ lhm, bf16* __restrict__ ctx2)
{
  // XCD swizzle: 512 blocks, 8 XCDs -> same-bh blocks land on one XCD's L2.
  const int blk = (blockIdx.x & 7) * 64 + (blockIdx.x >> 3);
  const int bh = blk >> 3, qb = blk & 7;
  const int tid = threadIdx.x;
  const int w = tid >> 6, lane = tid & 63;
  const int lq = lane & 31, hi = lane >> 5;
  const int b = bh >> 4, h = bh & 15;
  const int q0 = qb * 128 + w * 32;

  __shared__ __align__(16) bf16 sK[2][4096];   // 32 keys x [hi64|lo64] (chunk-swizzled rows)
  __shared__ __align__(16) bf16 sV[2][4096];   // 64 d x [32 hi|32 lo] (chunk-swizzled rows)

  // Q fragments (B-operand): lane holds row q0+lq, d-elems (hi*8 + j) of each 16-slice
  const bf16* qp = q2 + ((size_t)bh * SEQ_ + q0 + lq) * 128;
  bf16x8 qh[4], ql[4];
  #pragma unroll
  for (int s = 0; s < 4; ++s) {
    qh[s] = *(const bf16x8*)(qp + s * 16 + hi * 8);
    ql[s] = *(const bf16x8*)(qp + 64 + s * 16 + hi * 8);
  }

  const bf16* kp = k2 + (size_t)bh * SEQ_ * 128;
  const bf16* vp = vT2 + (size_t)bh * HD_ * 2048;
  const float* mp = mask + ((size_t)b * SEQ_ + q0 + lq) * SEQ_;

  // cooperative stage of one 32-key tile (K 8KB + V 8KB), pre-swizzled source
  auto stage = [&](int buf, int kb) {
    #pragma unroll
    for (int i = 0; i < 2; ++i) {
      int c = i * 256 + w * 64 + lane;
      // K: 256B rows; chunk swizzle c' = c ^ ((c>>4)&7)
      int cs = c ^ ((c >> 4) & 7);
      __builtin_amdgcn_global_load_lds((const void*)(kp + (size_t)kb * 128 + cs * 8),
                                       (void*)&sK[buf][(size_t)(i * 256 + w * 64) * 8], 16, 0, 0);
      // V: 128B rows [d][8 parts]; part swizzle p' = p ^ (d&7)
      int d = c >> 3, p = (c & 7) ^ (d & 7);
      const bf16* vsrc = vp + (size_t)d * 2048 + (p < 4 ? kb + p * 8 : 1024 + kb + (p - 4) * 8);
      __builtin_amdgcn_global_load_lds((const void*)vsrc,
                                       (void*)&sV[buf][(size_t)(i * 256 + w * 64) * 8], 16, 0, 0);
    }
  };

  float m_run = -1e30f, l_run = 0.f;
  f32x16 ot[2] = {};

  // mask prefetch: lane's query row, 16 keys at {8*r4 + 4*hi + 0..3}
  float4 mreg[4];
  #pragma unroll
  for (int r4 = 0; r4 < 4; ++r4)
    mreg[r4] = *(const float4*)(mp + 8 * r4 + 4 * hi);

  stage(0, 0);
  __syncthreads();

  for (int kc = 0; kc < SEQ_ / 32; ++kc) {
    const int kb = kc * 32;
    const int cur = kc & 1;
    if (kc + 1 < SEQ_ / 32) stage(cur ^ 1, kb + 32);

    const char* kbase = (const char*)sK[cur];
    const char* vbase = (const char*)sV[cur];

    // ---- QK^T (S^T): A = K rows, B = Q regs ----
    f32x16 st = {};
    __builtin_amdgcn_s_setprio(1);
    #pragma unroll
    for (int s = 0; s < 4; ++s) {
      int gh = s * 2 + hi, gl = 8 + s * 2 + hi;
      bf16x8 kh = *(const bf16x8*)(kbase + lq * 256 + ((gh ^ (lq & 7)) << 4));
      bf16x8 kl = *(const bf16x8*)(kbase + lq * 256 + ((gl ^ (lq & 7)) << 4));
      st = __builtin_amdgcn_mfma_f32_32x32x16_bf16(kh, qh[s], st, 0, 0, 0);
      st = __builtin_amdgcn_mfma_f32_32x32x16_bf16(kh, ql[s], st, 0, 0, 0);
      st = __builtin_amdgcn_mfma_f32_32x32x16_bf16(kl, qh[s], st, 0, 0, 0);
    }
    __builtin_amdgcn_s_setprio(0);
    // mask: st[reg] has key (reg&3)+8*(reg>>2)+4*hi
    #pragma unroll
    for (int reg = 0; reg < 16; ++reg)
      st[reg] = fmaf(((const float*)&mreg[reg >> 2])[reg & 3], L2E_, st[reg]);
    if (kc + 1 < SEQ_ / 32) {
      #pragma unroll
      for (int r4 = 0; r4 < 4; ++r4)
        mreg[r4] = *(const float4*)(mp + kb + 32 + 8 * r4 + 4 * hi);
    }

    // ---- softmax: per-lane (one query) ----
    float cm = st[0];
    #pragma unroll
    for (int reg = 1; reg < 16; ++reg) cm = fmaxf(cm, st[reg]);
    cm = fmaxf(cm, __shfl_xor(cm, 32, 64));
    float mnew = fmaxf(m_run, cm);
    float alpha = exp2f(m_run - mnew);
    float p[16];
    #pragma unroll
    for (int reg = 0; reg < 16; ++reg) p[reg] = exp2f(st[reg] - mnew);
    float rs = p[0];
    #pragma unroll
    for (int reg = 1; reg < 16; ++reg) rs += p[reg];
    rs += __shfl_xor(rs, 32, 64);
    l_run = l_run * alpha + rs; m_run = mnew;
    #pragma unroll
    for (int i = 0; i < 16; ++i) { ot[0][i] *= alpha; ot[1][i] *= alpha; }

    // ---- P -> bf16 hi/lo packs, redistribute for PV B-operand ----
    unsigned hA0 = pk2h(p[0], p[1]),  hA1 = pk2h(p[2], p[3]);
    unsigned hB0 = pk2h(p[4], p[5]),  hB1 = pk2h(p[6], p[7]);
    unsigned hC0 = pk2h(p[8], p[9]),  hC1 = pk2h(p[10], p[11]);
    unsigned hD0 = pk2h(p[12], p[13]), hD1 = pk2h(p[14], p[15]);
    unsigned lA0 = pk2l(p[0], p[1]),  lA1 = pk2l(p[2], p[3]);
    unsigned lB0 = pk2l(p[4], p[5]),  lB1 = pk2l(p[6], p[7]);
    unsigned lC0 = pk2l(p[8], p[9]),  lC1 = pk2l(p[10], p[11]);
    unsigned lD0 = pk2l(p[12], p[13]), lD1 = pk2l(p[14], p[15]);
    // exchange: hi=0 needs partner A, hi=1 needs partner B (slice0); C/D for slice1
    unsigned x0 = (unsigned)__shfl_xor((int)(hi ? hA0 : hB0), 32, 64);
    unsigned x1 = (unsigned)__shfl_xor((int)(hi ? hA1 : hB1), 32, 64);
    unsigned x2 = (unsigned)__shfl_xor((int)(hi ? hC0 : hD0), 32, 64);
    unsigned x3 = (unsigned)__shfl_xor((int)(hi ? hC1 : hD1), 32, 64);
    unsigned y0 = (unsigned)__shfl_xor((int)(hi ? lA0 : lB0), 32, 64);
    unsigned y1 = (unsigned)__shfl_xor((int)(hi ? lA1 : lB1), 32, 64);
    unsigned y2 = (unsigned)__shfl_xor((int)(hi ? lC0 : lD0), 32, 64);
    unsigned y3 = (unsigned)__shfl_xor((int)(hi ? lC1 : lD1), 32, 64);
    bf16x8 pb0h = hi ? mk8(x0, x1, hB0, hB1) : mk8(hA0, hA1, x0, x1);
    bf16x8 pb1h = hi ? mk8(x2, x3, hD0, hD1) : mk8(hC0, hC1, x2, x3);
    bf16x8 pb0l = hi ? mk8(y0, y1, lB0, lB1) : mk8(lA0, lA1, y0, y1);
    bf16x8 pb1l = hi ? mk8(y2, y3, lD0, lD1) : mk8(lC0, lC1, y2, y3);

    // ---- PV (O^T): A = V^T rows from LDS, B = P packs ----
    __builtin_amdgcn_s_setprio(1);
    #pragma unroll
    for (int ks = 0; ks < 2; ++ks) {
      bf16x8 pbh = ks ? pb1h : pb0h;
      bf16x8 pbl = ks ? pb1l : pb0l;
      #pragma unroll
      for (int t = 0; t < 2; ++t) {
        int row = t * 32 + lq;
        int gh = ks * 2 + hi, gl = 4 + ks * 2 + hi;
        bf16x8 vh = *(const bf16x8*)(vbase + row * 128 + ((gh ^ (row & 7)) << 4));
        bf16x8 vl = *(const bf16x8*)(vbase + row * 128 + ((gl ^ (row & 7)) << 4));
        ot[t] = __builtin_amdgcn_mfma_f32_32x32x16_bf16(vh, pbh, ot[t], 0, 0, 0);
        ot[t] = __builtin_amdgcn_mfma_f32_32x32x16_bf16(vh, pbl, ot[t], 0, 0, 0);
        ot[t] = __builtin_amdgcn_mfma_f32_32x32x16_bf16(vl, pbh, ot[t], 0, 0, 0);
      }
    }
    __builtin_amdgcn_s_setprio(0);

    __syncthreads();   // drains staging (vmcnt) + LDS reads before buffer swap
  }

  // ---- epilogue: O^T col=lane&31=query (in-lane l_run), row=d ----
  const float rln = lhm[h] / l_run;
  bf16* base = ctx2 + ((size_t)b * SEQ_ + q0 + lq) * 2048;
  #pragma unroll
  for (int t = 0; t < 2; ++t)
    #pragma unroll
    for (int reg = 0; reg < 16; ++reg) {
      int d = (reg & 3) + 8 * (reg >> 2) + 4 * hi + 32 * t;
      int col = h * HD_ + d;
      float y = ot[t][reg] * rln;
      bf16 yh = (bf16)y, yl = (bf16)(y - (float)yh);
      base[col] = yh; base[1024 + col] = yl;
    }
}

// ============================ layernorm+gate / route / final ============================
DEV float blockReduceSum(float v, int tid, float* sm)
{
  #pragma unroll
  for (int d = 1; d < 64; d <<= 1) v += __shfl_xor(v, d, 64);
  if ((tid & 63) == 0) sm[tid >> 6] = v;
  __syncthreads();
  float r = sm[0] + sm[1] + sm[2] + sm[3];
  __syncthreads();
  return r;
}

// OPROJ-reduce + LN1 + gate fused: z = hidden + P0 + P1 + ob; h = LN(z); gate from h.
__global__ __launch_bounds__(256)
void k_ln1gate(const float* __restrict__ resid, const float* __restrict__ Pp, const float* __restrict__ ob,
               const float* __restrict__ gam, const float* __restrict__ bet,
               const float* __restrict__ gw, const float* __restrict__ gb, const int* __restrict__ idxes,
               float* __restrict__ h, bf16* __restrict__ hb,
               float* __restrict__ gv, int* __restrict__ gi)
{
  __shared__ float sm[4];
  __shared__ float red[4][4];
  int t = blockIdx.x, tid = threadIdx.x;
  constexpr size_t CH = 4096ull * 1024ull;
  float4 rv = *(const float4*)(resid + (size_t)t * 1024 + tid * 4);
  float4 p0 = *(const float4*)(Pp + (size_t)t * 1024 + tid * 4);
  float4 p1 = *(const float4*)(Pp + CH + (size_t)t * 1024 + tid * 4);
  float4 bo = *(const float4*)(ob + tid * 4);
  float z0 = rv.x + p0.x + p1.x + bo.x;
  float z1 = rv.y + p0.y + p1.y + bo.y;
  float z2 = rv.z + p0.z + p1.z + bo.z;
  float z3 = rv.w + p0.w + p1.w + bo.w;
  float mean = blockReduceSum(z0 + z1 + z2 + z3, tid, sm) * (1.f / 1024.f);
  float d0 = z0 - mean, d1 = z1 - mean, d2 = z2 - mean, d3 = z3 - mean;
  float var = blockReduceSum(d0*d0 + d1*d1 + d2*d2 + d3*d3, tid, sm) * (1.f / 1024.f);
  float inv = rsqrtf(var + 1e-5f);
  float4 g4 = *(const float4*)(gam + tid * 4);
  float4 b4 = *(const float4*)(bet + tid * 4);
  float y0 = d0 * inv * g4.x + b4.x, y1 = d1 * inv * g4.y + b4.y;
  float y2 = d2 * inv * g4.z + b4.z, y3 = d3 * inv * g4.w + b4.w;
  float4 yo; yo.x = y0; yo.y = y1; yo.z = y2; yo.w = y3;
  *(float4*)(h + (size_t)t * 1024 + tid * 4) = yo;
  bf16x4v hv; hv[0] = (bf16)y0; hv[1] = (bf16)y1; hv[2] = (bf16)y2; hv[3] = (bf16)y3;
  *(bf16x4v*)(hb + (size_t)t * 1024 + tid * 4) = hv;

  // ---- gate ----
  int ds = idxes[t >> 10];
  const float* wg = gw + (size_t)ds * 4096;
  float a[4];
  #pragma unroll
  for (int e = 0; e < 4; ++e) {
    float4 wv = *(const float4*)(wg + e * 1024 + tid * 4);
    a[e] = y0 * wv.x + y1 * wv.y + y2 * wv.z + y3 * wv.w;
  }
  int lane = tid & 63, wid = tid >> 6;
  #pragma unroll
  for (int e = 0; e < 4; ++e) {
    float vv = a[e];
    #pragma unroll
    for (int d = 1; d < 64; d <<= 1) vv += __shfl_xor(vv, d, 64);
    if (lane == 0) red[wid][e] = vv;
  }
  __syncthreads();
  if (tid == 0) {
    float lg[4];
    #pragma unroll
    for (int e = 0; e < 4; ++e) lg[e] = red[0][e] + red[1][e] + red[2][e] + red[3][e] + gb[ds * 4 + e];
    int best = 0; float bv = lg[0];
    #pragma unroll
    for (int e = 1; e < 4; ++e) if (lg[e] > bv) { bv = lg[e]; best = e; }
    float se = 0.f;
    #pragma unroll
    for (int e = 0; e < 4; ++e) se += expf(lg[e] - bv);
    gv[t] = 1.f / se;
    gi[t] = best;
  }
}

// Single-block routing: count -> segments -> scatter (+ inverse map token->expert row).
__global__ __launch_bounds__(1024)
void k_route_all(const int* __restrict__ gi, int* __restrict__ meta,
                 int* __restrict__ perm, int* __restrict__ inv)
{
  __shared__ int cnt[4], seg[5], cur[4];
  int tid = threadIdx.x;
  if (tid < 4) { cnt[tid] = 0; cur[tid] = 0; }
  __syncthreads();
  #pragma unroll
  for (int k = 0; k < 4; ++k) atomicAdd(&cnt[gi[tid + k * 1024]], 1);
  #pragma unroll
  for (int k = 0; k < 5; ++k) { int i = tid + k * 1024; if (i < 4608) perm[i] = -1; }
  __syncthreads();
  if (tid == 0) {
    int s = 0;
    #pragma unroll
    for (int e = 0; e < 4; ++e) { seg[e] = s; s += (cnt[e] + 127) & ~127; }
    seg[4] = s;
    #pragma unroll
    for (int e = 0; e < 5; ++e) meta[8 + e] = seg[e];
  }
  __syncthreads();
  #pragma unroll
  for (int k = 0; k < 4; ++k) {
    int t = tid + k * 1024;
    int e = gi[t];
    int p = atomicAdd(&cur[e], 1);
    int rowp = seg[e] + p;
    perm[rowp] = t;
    inv[t] = rowp;
  }
}

// Final: reduce 2 split-K partials x (shared row + expert row) + fc2b, then LN2 * gate.
__global__ __launch_bounds__(256)
void k_final(const float* __restrict__ h, const bf16* __restrict__ P,
             const float* __restrict__ b2, const float* __restrict__ gam,
             const float* __restrict__ bet, const float* __restrict__ gv,
             const int* __restrict__ inv, float* __restrict__ out)
{
  __shared__ float sm[4];
  int t = blockIdx.x, tid = threadIdx.x;
  constexpr size_t CH = 8704ull * 1024ull;
  int er = 4096 + inv[t];
  bf16x4v q0 = *(const bf16x4v*)(P + (size_t)t * 1024 + tid * 4);
  bf16x4v q1 = *(const bf16x4v*)(P + CH + (size_t)t * 1024 + tid * 4);
  bf16x4v q2 = *(const bf16x4v*)(P + (size_t)er * 1024 + tid * 4);
  bf16x4v q3 = *(const bf16x4v*)(P + CH + (size_t)er * 1024 + tid * 4);
  float4 a = *(const float4*)(h + (size_t)t * 1024 + tid * 4);
  float4 bb = *(const float4*)(b2 + tid * 4);
  float z0 = a.x + (float)q0[0] + (float)q1[0] + (float)q2[0] + (float)q3[0] + bb.x;
  float z1 = a.y + (float)q0[1] + (float)q1[1] + (float)q2[1] + (float)q3[1] + bb.y;
  float z2 = a.z + (float)q0[2] + (float)q1[2] + (float)q2[2] + (float)q3[2] + bb.z;
  float z3 = a.w + (float)q0[3] + (float)q1[3] + (float)q2[3] + (float)q3[3] + bb.w;
  float mean = blockReduceSum(z0 + z1 + z2 + z3, tid, sm) * (1.f / 1024.f);
  float d0 = z0 - mean, d1 = z1 - mean, d2 = z2 - mean, d3 = z3 - mean;
  float var = blockReduceSum(d0*d0 + d1*d1 + d2*d2 + d3*d3, tid, sm) * (1.f / 1024.f);
  float invd = rsqrtf(var + 1e-5f);
  float4 g4 = *(const float4*)(gam + tid * 4);
  float4 b4 = *(const float4*)(bet + tid * 4);
  float gval = gv[t];
  float4 r;
  r.x = gval * (d0 * invd * g4.x + b4.x);
  r.y = gval * (d1 * invd * g4.y + b4.y);
  r.z = gval * (d2 * invd * g4.z + b4.z);
  r.w = gval * (d3 * invd * g4.w + b4.w);
  *(float4*)(out + (size_t)t * 1024 + tid * 4) = r;
}

// ============================ host ============================
extern "C" void kernel_launch(void* const* d_in, const int* in_sizes, int n_in,
                              void* d_out, int out_size, void* d_ws, size_t ws_size,
                              hipStream_t stream)
{
  const float* hidden = (const float*)d_in[0];
  const float* mask   = (const float*)d_in[1];
  const float* lhm    = (const float*)d_in[2];
  const int*   idxes  = (const int*)d_in[3];
  const float* qw = (const float*)d_in[4];
  const float* kw = (const float*)d_in[5];
  const float* vw = (const float*)d_in[6];
  const float* ow = (const float*)d_in[7];
  const float* fc1w  = (const float*)d_in[8];
  const float* fc2w  = (const float*)d_in[9];
  const float* efc1w = (const float*)d_in[10];
  const float* efc2w = (const float*)d_in[11];
  const float* gatew = (const float*)d_in[12];
  const float* qb = (const float*)d_in[13];
  const float* kb = (const float*)d_in[14];
  const float* vb = (const float*)d_in[15];
  const float* ob = (const float*)d_in[16];
  const float* fc1b  = (const float*)d_in[17];
  const float* fc2b  = (const float*)d_in[18];
  const float* efc1b = (const float*)d_in[19];
  const float* gateb = (const float*)d_in[20];
  const float* ln1g = (const float*)d_in[21];
  const float* ln1b = (const float*)d_in[22];
  const float* ln2g = (const float*)d_in[23];
  const float* ln2b = (const float*)d_in[24];
  float* out = (float*)d_out;
  char* ws = (char*)d_ws;

  constexpr size_t MB = 1024ull * 1024ull;
  // persistent
  constexpr size_t O_H    = 0;                     // fp32 h [4096][1024]
  constexpr size_t O_HBF  = O_H + 16 * MB;         // bf16 h
  constexpr size_t O_GV   = O_HBF + 8 * MB;
  constexpr size_t O_GI   = O_GV + 16 * 1024;
  constexpr size_t O_PERM = O_GI + 16 * 1024;      // 4608 ints
  constexpr size_t O_META = O_PERM + 18432;
  constexpr size_t O_INV  = O_META + 256;          // 4096 ints
  constexpr size_t O_U    = (O_INV + 16384 + 255) & ~255ull;
  // attention-phase overlay (contiguous split-bf16 block: X2|WQ2|WK2|WV2|WO2)
  constexpr size_t O_X2   = O_U;                   // [4096][2048] bf16
  constexpr size_t O_WQ2  = O_X2 + 16 * MB;        // [3072][2048]: Q,K,V weights contiguous
  constexpr size_t O_Q2   = O_WQ2 + 16 * MB;       // [B*NH*L][128]
  constexpr size_t O_K2   = O_Q2 + 16 * MB;
  constexpr size_t O_VT2  = O_K2 + 16 * MB;        // [B*NH*HD][2048]
  constexpr size_t O_CTX2 = O_VT2 + 16 * MB;       // [4096][2048]
  constexpr size_t O_HPRE = O_CTX2 + 16 * MB;      // fp32 2 x [4096][1024] OPROJ split-K partials
  constexpr size_t O_WO2  = O_WQ2 + 12 * MB;       // ow rows inside the contiguous block
  // MoE-phase overlay (same region — attn buffers dead by then)
  constexpr size_t O_W1B  = O_U;                   // [fc1|efc1x4|fc2|efc2x4] contiguous 80 MB bf16
  constexpr size_t O_WE1B = O_W1B + 8 * MB;
  constexpr size_t O_W2B  = O_WE1B + 32 * MB;
  constexpr size_t O_WE2B = O_W2B + 8 * MB;
  constexpr size_t O_HHS  = O_WE2B + 32 * MB;      // [4096][4096] bf16 (shared)  — contiguous with
  constexpr size_t O_HHE  = O_HHS + 32 * MB;       // [4608][4096] bf16 (expert)  — HHS (rows 4096+)
  constexpr size_t O_P    = O_HHE + 36 * MB;       // 2 x [8704][1024] bf16 split-K partials (34 MB)
  (void)ws_size; (void)in_sizes; (void)n_in; (void)out_size;

  dim3 blk(256);
  // ---- phase 1: attention-path conversions (hi|lo split, ONE launch, contiguous dst) ----
  k_cvt_split_all<<<8192, 256, 0, stream>>>(hidden, qw, kw, vw, ow, (bf16*)(ws + O_X2));

  // ---- phase 2: fused QKV projection (N=3072, 768 blocks) ----
  const float qscale = 0.125f * L2E_;   // fold softmax scale and log2e into Q
  k_gemm<EPI_QKV, true, 128, 128, true><<<dim3(32, 24), blk, 0, stream>>>(
      (bf16*)(ws + O_X2), (bf16*)(ws + O_WQ2), qb, kb, vb, nullptr,
      nullptr, (bf16*)(ws + O_Q2), (bf16*)(ws + O_K2), (bf16*)(ws + O_VT2),
      nullptr, nullptr, 2048, 96, qscale);

  // ---- phase 3: attention (swapped-QK^T 32x32 structure, 512 blocks) ----
  k_attn<<<512, 256, 0, stream>>>((bf16*)(ws + O_Q2), (bf16*)(ws + O_K2), (bf16*)(ws + O_VT2),
                                  mask, lhm, (bf16*)(ws + O_CTX2));

  // ---- phase 4: output projection (split-K x2, fp32 partials), then fused reduce+LN1+gate ----
  k_gemm<EPI_OPROJ, true, 128, 64, true><<<dim3(32, 16, 2), blk, 0, stream>>>(
      (bf16*)(ws + O_CTX2), (bf16*)(ws + O_WO2), nullptr, nullptr, nullptr, nullptr,
      (float*)(ws + O_HPRE), nullptr, nullptr, nullptr, nullptr, nullptr, 2048, 48, 1.0f);
  k_ln1gate<<<4096, 256, 0, stream>>>(hidden, (float*)(ws + O_HPRE), ob, ln1g, ln1b,
                                      gatew, gateb, idxes,
                                      (float*)(ws + O_H), (bf16*)(ws + O_HBF),
                                      (float*)(ws + O_GV), (int*)(ws + O_GI));

  // ---- phase 5: MoE weight conversion (ONE launch), routing (ONE block) ----
  k_cvt4<<<40960, 256, 0, stream>>>(fc1w, efc1w, fc2w, efc2w, (bf16*)(ws + O_W1B));
  k_route_all<<<1, 1024, 0, stream>>>((int*)(ws + O_GI), (int*)(ws + O_META),
                                      (int*)(ws + O_PERM), (int*)(ws + O_INV));

  // ---- phase 6: fused shared+expert FFN (NEWSYNC counted-vmcnt pipeline) ----
  // FF1: single launch, TM=128, plain 2D grid (68,32)
  k_gemm<EPI_FF1, false, 128, 128, true><<<dim3(68, 32), blk, 0, stream>>>(
      (bf16*)(ws + O_HBF), (bf16*)(ws + O_W1B), fc1b, efc1b, nullptr, nullptr,
      nullptr, (bf16*)(ws + O_HHS), nullptr, nullptr,
      (int*)(ws + O_PERM), (int*)(ws + O_META) + 8, 1024, 32, 1.0f);
  // FF2: split-K x2 into bf16 partials — 1088 blocks, A-grouped per XCD
  k_gemm<EPI_FF2, false, 128, 128, true><<<dim3(1088), blk, 0, stream>>>(
      (bf16*)(ws + O_HHS), (bf16*)(ws + O_W2B), nullptr, nullptr, nullptr, nullptr,
      nullptr, nullptr, (bf16*)(ws + O_P), nullptr,
      nullptr, (int*)(ws + O_META) + 8, 4096, 64, 1.0f);

  // ---- phase 7: final reduce + LN2 * gate_value ----
  k_final<<<4096, 256, 0, stream>>>((float*)(ws + O_H), (bf16*)(ws + O_P), fc2b, ln2g, ln2b,
                                    (float*)(ws + O_GV), (int*)(ws + O_INV), out);
}